// Round 5
// baseline (503.343 us; speedup 1.0000x reference)
//
#include <hip/hip_runtime.h>
#include <math.h>

#define EPS 1e-4f

__device__ __forceinline__ float sigmoidf_(float x){ return 1.0f/(1.0f+expf(-x)); }

// ---- ordered-uint mapping for float atomic min/max ----
__device__ __forceinline__ unsigned f2u_(float f){
    unsigned u = __float_as_uint(f);
    return (u & 0x80000000u) ? ~u : (u | 0x80000000u);
}
__device__ __forceinline__ float u2f_(unsigned u){
    unsigned b = (u & 0x80000000u) ? (u & 0x7FFFFFFFu) : ~u;
    return __uint_as_float(b);
}

// ================= min/max of pos =================
__global__ void minmax_kernel(const float* __restrict__ p, int n, unsigned* mm){
    float lo = INFINITY, hi = -INFINITY;
    for (int i = blockIdx.x*blockDim.x + threadIdx.x; i < n; i += gridDim.x*blockDim.x){
        float v = p[i]; lo = fminf(lo, v); hi = fmaxf(hi, v);
    }
    for (int off = 32; off > 0; off >>= 1){
        lo = fminf(lo, __shfl_down(lo, off));
        hi = fmaxf(hi, __shfl_down(hi, off));
    }
    __shared__ float slo[8], shi[8];
    int wid = threadIdx.x >> 6;
    if ((threadIdx.x & 63) == 0){ slo[wid] = lo; shi[wid] = hi; }
    __syncthreads();
    if (threadIdx.x == 0){
        int nw = blockDim.x >> 6;
        for (int w = 1; w < nw; w++){ lo = fminf(lo, slo[w]); hi = fmaxf(hi, shi[w]); }
        atomicMin(&mm[0], f2u_(lo));
        atomicMax(&mm[1], f2u_(hi));
    }
}

// ================= CSR build =================
__global__ void edge_rank(const int* __restrict__ ei, int* __restrict__ deg,
                          int* __restrict__ rank, int E){
    int e = blockIdx.x*blockDim.x + threadIdx.x;
    if (e >= E) return;
    rank[e] = atomicAdd(&deg[ei[E + e]], 1);
}

__global__ __launch_bounds__(256)
void scan_bsum(const int* __restrict__ deg, int* __restrict__ bsum, int N){
    int i = blockIdx.x*256 + threadIdx.x;
    int v = (i < N) ? deg[i] : 0;
    for (int o = 32; o > 0; o >>= 1) v += __shfl_down(v, o);
    __shared__ int ws[4];
    if ((threadIdx.x & 63) == 0) ws[threadIdx.x >> 6] = v;
    __syncthreads();
    if (threadIdx.x == 0) bsum[blockIdx.x] = ws[0] + ws[1] + ws[2] + ws[3];
}

__global__ __launch_bounds__(1024)
void scan_top(int* __restrict__ bsum, int NB){
    __shared__ int sh[1024];
    int t = threadIdx.x;
    int v = (t < NB) ? bsum[t] : 0;
    sh[t] = v;
    __syncthreads();
    for (int d = 1; d < 1024; d <<= 1){
        int u = (t >= d) ? sh[t - d] : 0;
        __syncthreads();
        sh[t] += u;
        __syncthreads();
    }
    if (t < NB) bsum[t] = sh[t] - v;
    if (t == 1023) bsum[NB] = sh[1023];
}

__global__ __launch_bounds__(256)
void scan_final(const int* __restrict__ deg, const int* __restrict__ bsum,
                int* __restrict__ off, int N, int NB){
    __shared__ int sh[256];
    int b = blockIdx.x;
    int i = b*256 + threadIdx.x;
    int v = (i < N) ? deg[i] : 0;
    sh[threadIdx.x] = v;
    __syncthreads();
    for (int d = 1; d < 256; d <<= 1){
        int u = (threadIdx.x >= d) ? sh[threadIdx.x - d] : 0;
        __syncthreads();
        sh[threadIdx.x] += u;
        __syncthreads();
    }
    if (i < N) off[i] = bsum[b] + sh[threadIdx.x] - v;    // exclusive
    if (b == 0 && threadIdx.x == 0) off[N] = bsum[NB];
}

// streaming pack + atomic-free scatter: slot = off[dst] + rank[e]
__global__ void edge_pack(const int* __restrict__ ei, const float* __restrict__ pseudo,
                          const float* __restrict__ x,
                          const int* __restrict__ rank, const int* __restrict__ off,
                          float4* __restrict__ rec4, int* __restrict__ recb, int E){
    int e = blockIdx.x*blockDim.x + threadIdx.x;
    if (e >= E) return;
    float p0 = pseudo[3*e], p1 = pseudo[3*e+1], p2 = pseudo[3*e+2];
    int s = ei[e], d = ei[E + e];
    float v0 = p0*4.f, v1 = p1*4.f, v2 = p2*4.f;
    float f0 = fminf(fmaxf(floorf(v0), 0.f), 3.f);
    float f1 = fminf(fmaxf(floorf(v1), 0.f), 3.f);
    float f2 = fminf(fmaxf(floorf(v2), 0.f), 3.f);
    int slot = off[d] + rank[e];
    rec4[slot] = make_float4(v0 - f0, v1 - f1, v2 - f2, x[s]);
    recb[slot] = ((int)f0*5 + (int)f1)*5 + (int)f2;
}

__device__ __forceinline__ int voxel_id(const float* __restrict__ pos, int n, int G,
                                        float start, float size){
    int g[3];
    #pragma unroll
    for (int k = 0; k < 3; k++){
        float gg = floorf((pos[(size_t)n*3 + k] - start) / size);
        gg = fminf(fmaxf(gg, 0.f), (float)(G - 1));
        g[k] = (int)gg;
    }
    return (g[0]*G + g[1])*G + g[2];
}

__device__ __forceinline__ void pool_geom(const unsigned* mm, int G, int mode,
                                          float& start, float& size){
    float mn = u2f_(mm[0]), mx = u2f_(mm[1]);
    if (mode == 0){ start = mn; size = (mx + 0.001f - mn) / (float)G; }
    else          { start = mn - 0.5f; size = mx - mn + 1.0f; }
}

__global__ void elist_node(const float* __restrict__ pos, int* __restrict__ head,
                           int* __restrict__ nxt, int N, int G, int mode,
                           const unsigned* __restrict__ mm){
    int n = blockIdx.x*blockDim.x + threadIdx.x;
    if (n >= N) return;
    float start, size; pool_geom(mm, G, mode, start, size);
    int v = voxel_id(pos, n, G, start, size);
    nxt[n] = atomicExch(&head[v], n);
}

// ===== fused spline gather + node finalize: 8 lanes per node (tid = n*8+k) =====
__global__ __launch_bounds__(256)
void spline_node_kernel(const float* __restrict__ x, const float4* __restrict__ rec4,
                        const int* __restrict__ recb, const int* __restrict__ off,
                        const float* __restrict__ W,
                        const float* __restrict__ root, const float* __restrict__ bias,
                        const float* __restrict__ lin_w, const float* __restrict__ lin_b,
                        float* __restrict__ pose, float* __restrict__ act, int N){
    __shared__ float Ws[125*17];
    for (int i = threadIdx.x; i < 125*16; i += blockDim.x)
        Ws[(i >> 4)*17 + (i & 15)] = W[i];
    __syncthreads();
    int t = blockIdx.x*blockDim.x + threadIdx.x;
    int n = t >> 3;
    int k = t & 7;
    if (n >= N) return;     // group-uniform guard (all 8 lanes share n)

    int o0 = off[n], o1 = off[n+1];

    float agg[16];
    #pragma unroll
    for (int o = 0; o < 16; o++) agg[o] = 0.f;

    for (int s = o0 + k; s < o1; s += 8){
        float4 rv = rec4[s];
        int base = recb[s];
        float fr0 = rv.x, fr1 = rv.y, fr2 = rv.z, xv = rv.w;
        #pragma unroll
        for (int b = 0; b < 8; b++){
            int b0 = (b >> 2) & 1, b1 = (b >> 1) & 1, b2 = b & 1;
            float w = (b0 ? fr0 : 1.f - fr0) * (b1 ? fr1 : 1.f - fr1) * (b2 ? fr2 : 1.f - fr2);
            w *= xv;
            const float* Wr = &Ws[(base + b0*25 + b1*5 + b2)*17];
            #pragma unroll
            for (int o = 0; o < 16; o++) agg[o] += w * Wr[o];
        }
    }

    // 8-lane reduction (lanes n*8..n*8+7)
    #pragma unroll
    for (int o = 0; o < 16; o++){
        agg[o] += __shfl_xor(agg[o], 1);
        agg[o] += __shfl_xor(agg[o], 2);
        agg[o] += __shfl_xor(agg[o], 4);
    }

    if (k != 0) return;

    float deg = fmaxf((float)(o1 - o0), 1.0f);
    float xs = x[n];
    float qv0 = lin_b[0], qv1 = lin_b[1], qv2 = lin_b[2], qv3 = lin_b[3];
    #pragma unroll
    for (int o = 0; o < 16; o++){
        float h = agg[o] / deg + xs * root[o] + bias[o];
        float e = (h > 0.f) ? h : expm1f(h);
        qv0 += e * lin_w[o*4 + 0];
        qv1 += e * lin_w[o*4 + 1];
        qv2 += e * lin_w[o*4 + 2];
        qv3 += e * lin_w[o*4 + 3];
    }
    float inv = 1.0f / (sqrtf(qv0*qv0 + qv1*qv1 + qv2*qv2 + qv3*qv3) + EPS);
    pose[(size_t)n*4 + 0] = qv0*inv;
    pose[(size_t)n*4 + 1] = qv1*inv;
    pose[(size_t)n*4 + 2] = qv2*inv;
    pose[(size_t)n*4 + 3] = qv3*inv;
    act[n] = xs;
}

// ====== capsule routing — per-node register-resident (large-N layers) ======
template<int I, int J>
__global__ __launch_bounds__(64)
void caps_node_kernel(const float* __restrict__ poseIn, const float* __restrict__ actIn,
                      const float* __restrict__ q,
                      float* __restrict__ poseOut, float* __restrict__ actOut, int N){
    __shared__ float qn[I*J*4];
    for (int t = threadIdx.x; t < I*J; t += blockDim.x){
        float qa=q[t*4], qb=q[t*4+1], qc=q[t*4+2], qd=q[t*4+3];
        float inv = 1.f/(sqrtf(qa*qa+qb*qb+qc*qc+qd*qd)+EPS);
        qn[t*4+0]=qa*inv; qn[t*4+1]=qb*inv; qn[t*4+2]=qc*inv; qn[t*4+3]=qd*inv;
    }
    __syncthreads();
    int n = blockIdx.x*blockDim.x + threadIdx.x;
    if (n >= N) return;

    float pr[I][J][4];
    float a[I];
    float b[I][J];
    #pragma unroll
    for (int i = 0; i < I; i++){
        float4 p = *reinterpret_cast<const float4*>(&poseIn[((size_t)n*I + i)*4]);
        a[i] = actIn[(size_t)n*I + i];
        #pragma unroll
        for (int j = 0; j < J; j++){
            const float* qq = &qn[(i*J + j)*4];
            float qx=qq[0], qy=qq[1], qz=qq[2], qw=qq[3];
            float tx = qw*p.x + qx*p.w + qy*p.z - qz*p.y;
            float ty = qw*p.y - qx*p.z + qy*p.w + qz*p.x;
            float tz = qw*p.z + qx*p.y - qy*p.x + qz*p.w;
            float tw = qw*p.w - qx*p.x - qy*p.y - qz*p.z;
            float inv = 1.f/(sqrtf(tx*tx+ty*ty+tz*tz+tw*tw)+EPS);
            pr[i][j][0]=tx*inv; pr[i][j][1]=ty*inv; pr[i][j][2]=tz*inv; pr[i][j][3]=tw*inv;
            b[i][j] = 0.f;
        }
    }

    float c[I][J], v[J][4];
    #pragma unroll
    for (int t = 0; t < 3; t++){
        #pragma unroll
        for (int i = 0; i < I; i++){
            float mb = -INFINITY;
            #pragma unroll
            for (int j = 0; j < J; j++) mb = fmaxf(mb, b[i][j]);
            float e[J]; float d = 0.f;
            #pragma unroll
            for (int j = 0; j < J; j++){ e[j] = expf(b[i][j] - mb); d += e[j]; }
            #pragma unroll
            for (int j = 0; j < J; j++) c[i][j] = a[i] * e[j] / d;
        }
        #pragma unroll
        for (int j = 0; j < J; j++){
            float s0=0.f, s1=0.f, s2=0.f, s3=0.f;
            #pragma unroll
            for (int i = 0; i < I; i++){
                s0 += c[i][j]*pr[i][j][0]; s1 += c[i][j]*pr[i][j][1];
                s2 += c[i][j]*pr[i][j][2]; s3 += c[i][j]*pr[i][j][3];
            }
            float inv = 1.f/(sqrtf(s0*s0+s1*s1+s2*s2+s3*s3)+EPS);
            v[j][0]=s0*inv; v[j][1]=s1*inv; v[j][2]=s2*inv; v[j][3]=s3*inv;
        }
        if (t < 2){
            #pragma unroll
            for (int i = 0; i < I; i++)
                #pragma unroll
                for (int j = 0; j < J; j++)
                    b[i][j] += pr[i][j][0]*v[j][0] + pr[i][j][1]*v[j][1]
                             + pr[i][j][2]*v[j][2] + pr[i][j][3]*v[j][3];
        }
    }

    #pragma unroll
    for (int j = 0; j < J; j++){
        float acc = 0.f;
        #pragma unroll
        for (int i = 0; i < I; i++)
            acc += c[i][j]*(pr[i][j][0]*v[j][0] + pr[i][j][1]*v[j][1]
                          + pr[i][j][2]*v[j][2] + pr[i][j][3]*v[j][3]);
        actOut[(size_t)n*J + j] = sigmoidf_(acc);
        *reinterpret_cast<float4*>(&poseOut[((size_t)n*J + j)*4]) =
            make_float4(v[j][0], v[j][1], v[j][2], v[j][3]);
    }
}

// ====== capsule routing — cooperative (small-N tail layers) ======
template<int I, int J, int NPB>
__global__ __launch_bounds__(NPB*I*J)
void caps_coop_kernel(const float* __restrict__ poseIn, const float* __restrict__ actIn,
                      const float* __restrict__ q, float* __restrict__ poseOut,
                      float* __restrict__ actOut, int N){
    const int IJ = I*J;
    const int tid = threadIdx.x;
    const int nl  = tid / IJ;
    const int li  = tid - nl*IJ;
    const int i   = li / J;
    const int j   = li - i*J;
    const int node = blockIdx.x*NPB + nl;
    const bool on = (node < N);

    __shared__ float redA[NPB][I*J];
    __shared__ float redB[NPB][I*J];
    __shared__ float cp[NPB][I*J*4];
    __shared__ float vsh[NPB][J*4];

    float prx=0.f, pry=0.f, prz=0.f, prw=0.f, ai=0.f;
    if (on){
        float qx = q[li*4+0], qy = q[li*4+1], qz = q[li*4+2], qw = q[li*4+3];
        float qinv = 1.0f/(sqrtf(qx*qx+qy*qy+qz*qz+qw*qw)+EPS);
        qx*=qinv; qy*=qinv; qz*=qinv; qw*=qinv;
        const float* pp = &poseIn[((size_t)node*I + i)*4];
        float rx=pp[0], ry=pp[1], rz=pp[2], rw=pp[3];
        ai = actIn[(size_t)node*I + i];
        float tx = qw*rx + qx*rw + qy*rz - qz*ry;
        float ty = qw*ry - qx*rz + qy*rw + qz*rx;
        float tz = qw*rz + qx*ry - qy*rx + qz*rw;
        float tw = qw*rw - qx*rx - qy*ry - qz*rz;
        float pinv = 1.0f/(sqrtf(tx*tx+ty*ty+tz*tz+tw*tw)+EPS);
        prx=tx*pinv; pry=ty*pinv; prz=tz*pinv; prw=tw*pinv;
    }

    float b = 0.f, c = 0.f;
    for (int t = 0; t < 3; t++){
        redA[nl][li] = b;
        __syncthreads();
        float mb = -INFINITY;
        #pragma unroll
        for (int jj = 0; jj < J; jj++) mb = fmaxf(mb, redA[nl][i*J+jj]);
        float e = expf(b - mb);
        redB[nl][li] = e;
        __syncthreads();
        float s = 0.f;
        #pragma unroll
        for (int jj = 0; jj < J; jj++) s += redB[nl][i*J+jj];
        c = ai * e / s;
        cp[nl][li*4+0] = c*prx; cp[nl][li*4+1] = c*pry;
        cp[nl][li*4+2] = c*prz; cp[nl][li*4+3] = c*prw;
        __syncthreads();
        for (int idx = li; idx < J*4; idx += IJ){
            int jj = idx >> 2, comp = idx & 3;
            float acc = 0.f;
            #pragma unroll
            for (int ii = 0; ii < I; ii++) acc += cp[nl][(ii*J+jj)*4+comp];
            vsh[nl][idx] = acc;
        }
        __syncthreads();
        if (li < J){
            float a0=vsh[nl][li*4], a1=vsh[nl][li*4+1], a2=vsh[nl][li*4+2], a3=vsh[nl][li*4+3];
            float inv = 1.0f/(sqrtf(a0*a0+a1*a1+a2*a2+a3*a3)+EPS);
            vsh[nl][li*4]=a0*inv; vsh[nl][li*4+1]=a1*inv;
            vsh[nl][li*4+2]=a2*inv; vsh[nl][li*4+3]=a3*inv;
        }
        __syncthreads();
        if (t < 2){
            b += prx*vsh[nl][j*4] + pry*vsh[nl][j*4+1] + prz*vsh[nl][j*4+2] + prw*vsh[nl][j*4+3];
            __syncthreads();
        } else {
            redA[nl][li] = c*(prx*vsh[nl][j*4] + pry*vsh[nl][j*4+1]
                            + prz*vsh[nl][j*4+2] + prw*vsh[nl][j*4+3]);
            __syncthreads();
            if (li < J && on){
                float acc = 0.f;
                #pragma unroll
                for (int ii = 0; ii < I; ii++) acc += redA[nl][ii*J+li];
                actOut[(size_t)node*J + li] = sigmoidf_(acc);
                poseOut[((size_t)node*J+li)*4+0] = vsh[nl][li*4+0];
                poseOut[((size_t)node*J+li)*4+1] = vsh[nl][li*4+1];
                poseOut[((size_t)node*J+li)*4+2] = vsh[nl][li*4+2];
                poseOut[((size_t)node*J+li)*4+3] = vsh[nl][li*4+3];
            }
        }
    }
}

// ---------- pool1 (V=32768, ~1.5 nodes/voxel): thread-per-voxel linked-list gather ----------
template<int J>
__global__ __launch_bounds__(256)
void pool1_gather_kernel(const float* __restrict__ pose, const float* __restrict__ act,
                         const float* __restrict__ pos,
                         const int* __restrict__ head, const int* __restrict__ nxt,
                         float* __restrict__ poseOut, float* __restrict__ actOut,
                         float* __restrict__ posOut, int V){
    int v = blockIdx.x*blockDim.x + threadIdx.x;
    if (v >= V) return;

    float s[J][4], w[J], ps0=0.f, ps1=0.f, ps2=0.f;
    #pragma unroll
    for (int j = 0; j < J; j++){ s[j][0]=0.f; s[j][1]=0.f; s[j][2]=0.f; s[j][3]=0.f; w[j]=0.f; }

    int cnt = 0;
    for (int n = head[v]; n >= 0; n = nxt[n]){
        const float* pb = &pose[(size_t)n*J*4];
        const float* ab = &act[(size_t)n*J];
        #pragma unroll
        for (int j = 0; j < J; j++){
            float aj = ab[j];
            s[j][0] += aj*pb[j*4+0];
            s[j][1] += aj*pb[j*4+1];
            s[j][2] += aj*pb[j*4+2];
            s[j][3] += aj*pb[j*4+3];
            w[j] += aj;
        }
        ps0 += pos[(size_t)n*3+0];
        ps1 += pos[(size_t)n*3+1];
        ps2 += pos[(size_t)n*3+2];
        cnt++;
    }
    #pragma unroll
    for (int j = 0; j < J; j++){
        float inv = 1.0f/(sqrtf(s[j][0]*s[j][0]+s[j][1]*s[j][1]+
                                s[j][2]*s[j][2]+s[j][3]*s[j][3])+EPS);
        s[j][0]*=inv; s[j][1]*=inv; s[j][2]*=inv; s[j][3]*=inv;
    }
    float ag[J];
    #pragma unroll
    for (int j = 0; j < J; j++) ag[j] = 0.f;
    for (int n = head[v]; n >= 0; n = nxt[n]){
        const float* pb = &pose[(size_t)n*J*4];
        const float* ab = &act[(size_t)n*J];
        #pragma unroll
        for (int j = 0; j < J; j++){
            float agree = pb[j*4+0]*s[j][0] + pb[j*4+1]*s[j][1]
                        + pb[j*4+2]*s[j][2] + pb[j*4+3]*s[j][3];
            ag[j] += ab[j]*agree;
        }
    }
    #pragma unroll
    for (int j = 0; j < J; j++){
        size_t o = (size_t)v*J + j;
        actOut[o] = sigmoidf_(ag[j] / (w[j] + EPS));
        poseOut[o*4+0] = s[j][0];
        poseOut[o*4+1] = s[j][1];
        poseOut[o*4+2] = s[j][2];
        poseOut[o*4+3] = s[j][3];
    }
    float c = (float)cnt + EPS;
    posOut[(size_t)v*3+0] = ps0 / c;
    posOut[(size_t)v*3+1] = ps1 / c;
    posOut[(size_t)v*3+2] = ps2 / c;
}

// ---------- pools 2-3 (small V, heavy skew): node-parallel LDS-privatized ----------
template<int V, int J, int CH, int NCHUNK>
__global__ void pool_priv1(const float4* __restrict__ poseIn, const float* __restrict__ actIn,
                           const float* __restrict__ posIn,
                           float* __restrict__ s, float* __restrict__ wsum,
                           float* __restrict__ cnt, float* __restrict__ psum,
                           int N, int G, int mode, const unsigned* __restrict__ mm){
    __shared__ float s_[V*CH*4];
    __shared__ float wsum_[V*CH];
    __shared__ float cnt_[V];
    __shared__ float psum_[V*3];
    const int chunk = blockIdx.x % NCHUNK;
    const int slice = blockIdx.x / NCHUNK;
    const int nslices = gridDim.x / NCHUNK;
    const int c0 = chunk * CH;

    for (int t = threadIdx.x; t < V*CH*4; t += blockDim.x) s_[t] = 0.f;
    for (int t = threadIdx.x; t < V*CH; t += blockDim.x) wsum_[t] = 0.f;
    if (chunk == 0){
        for (int t = threadIdx.x; t < V; t += blockDim.x) cnt_[t] = 0.f;
        for (int t = threadIdx.x; t < V*3; t += blockDim.x) psum_[t] = 0.f;
    }
    __syncthreads();

    float start, size; pool_geom(mm, G, mode, start, size);
    int per = (N + nslices - 1) / nslices;
    int n0 = slice * per, n1 = min(N, n0 + per);

    for (int n = n0 + (int)threadIdx.x; n < n1; n += blockDim.x){
        int vid = voxel_id(posIn, n, G, start, size);
        #pragma unroll
        for (int jj = 0; jj < CH; jj++){
            int j = c0 + jj;
            float aj = actIn[(size_t)n*J + j];
            float4 p = poseIn[(size_t)n*J + j];
            int b = (vid*CH + jj)*4;
            atomicAdd(&s_[b+0], aj*p.x);
            atomicAdd(&s_[b+1], aj*p.y);
            atomicAdd(&s_[b+2], aj*p.z);
            atomicAdd(&s_[b+3], aj*p.w);
            atomicAdd(&wsum_[vid*CH + jj], aj);
        }
        if (chunk == 0){
            atomicAdd(&cnt_[vid], 1.0f);
            atomicAdd(&psum_[vid*3+0], posIn[(size_t)n*3+0]);
            atomicAdd(&psum_[vid*3+1], posIn[(size_t)n*3+1]);
            atomicAdd(&psum_[vid*3+2], posIn[(size_t)n*3+2]);
        }
    }
    __syncthreads();

    for (int t = threadIdx.x; t < V*CH*4; t += blockDim.x){
        float val = s_[t];
        if (val != 0.f){
            int v = t / (CH*4), r = t % (CH*4);
            atomicAdd(&s[((size_t)v*J + c0)*4 + r], val);
        }
    }
    for (int t = threadIdx.x; t < V*CH; t += blockDim.x){
        float val = wsum_[t];
        if (val != 0.f){
            int v = t / CH, jj = t % CH;
            atomicAdd(&wsum[(size_t)v*J + c0 + jj], val);
        }
    }
    if (chunk == 0){
        for (int t = threadIdx.x; t < V; t += blockDim.x)
            if (cnt_[t] != 0.f) atomicAdd(&cnt[t], cnt_[t]);
        for (int t = threadIdx.x; t < V*3; t += blockDim.x)
            if (psum_[t] != 0.f) atomicAdd(&psum[t], psum_[t]);
    }
}

template<int V, int J>
__global__ void pool_priv2(const float4* __restrict__ poseIn, const float* __restrict__ actIn,
                           const float* __restrict__ posIn, const float4* __restrict__ m,
                           float* __restrict__ agacc,
                           int N, int G, int mode, const unsigned* __restrict__ mm){
    __shared__ float ag_[V*J];
    for (int t = threadIdx.x; t < V*J; t += blockDim.x) ag_[t] = 0.f;
    __syncthreads();
    float start, size; pool_geom(mm, G, mode, start, size);
    int nslices = gridDim.x;
    int per = (N + nslices - 1) / nslices;
    int n0 = blockIdx.x * per, n1 = min(N, n0 + per);
    for (int n = n0 + (int)threadIdx.x; n < n1; n += blockDim.x){
        int vid = voxel_id(posIn, n, G, start, size);
        #pragma unroll
        for (int j = 0; j < J; j++){
            float4 p  = poseIn[(size_t)n*J + j];
            float4 mv = m[(size_t)vid*J + j];
            float agree = p.x*mv.x + p.y*mv.y + p.z*mv.z + p.w*mv.w;
            atomicAdd(&ag_[vid*J + j], actIn[(size_t)n*J + j]*agree);
        }
    }
    __syncthreads();
    for (int t = threadIdx.x; t < V*J; t += blockDim.x)
        if (ag_[t] != 0.f) atomicAdd(&agacc[t], ag_[t]);
}

__global__ void pool_m(const float* __restrict__ s, float* __restrict__ m, int VJ){
    int t = blockIdx.x*blockDim.x + threadIdx.x;
    if (t >= VJ) return;
    float a = s[(size_t)t*4], b = s[(size_t)t*4+1], c = s[(size_t)t*4+2], d = s[(size_t)t*4+3];
    float inv = 1.0f / (sqrtf(a*a + b*b + c*c + d*d) + EPS);
    m[(size_t)t*4]   = a*inv;
    m[(size_t)t*4+1] = b*inv;
    m[(size_t)t*4+2] = c*inv;
    m[(size_t)t*4+3] = d*inv;
}

__global__ void pool_fin(const float* __restrict__ agacc, const float* __restrict__ wsum,
                         const float* __restrict__ cnt, const float* __restrict__ psum,
                         float* __restrict__ actOut, float* __restrict__ posOut, int V, int J){
    int t = blockIdx.x*blockDim.x + threadIdx.x;
    if (t >= V*J) return;
    int v = t / J, j = t % J;
    actOut[t] = sigmoidf_(agacc[t] / (wsum[t] + EPS));
    if (j == 0){
        float c = cnt[v] + EPS;
        posOut[(size_t)v*3 + 0] = psum[(size_t)v*3 + 0] / c;
        posOut[(size_t)v*3 + 1] = psum[(size_t)v*3 + 1] / c;
        posOut[(size_t)v*3 + 2] = psum[(size_t)v*3 + 2] / c;
    }
}

// ---------- pool4 (NIN=8 -> V=1): thread-per-capsule, zero atomics ----------
// All NIN nodes map to voxel 0 (G=1), so each output capsule j is an independent
// 8-element reduction: one thread per j, two register-resident loops. Replaces the
// same-address-LDS-atomic fused kernel (round-4 evidence: that structure serializes).
template<int NIN, int J>
__global__ __launch_bounds__(64)
void pool4_tiny(const float* __restrict__ poseIn, const float* __restrict__ actIn,
                const float* __restrict__ posIn,
                float* __restrict__ poseOut, float* __restrict__ actOut,
                float* __restrict__ posOut){
    int t = threadIdx.x;
    if (t < J){
        float s0=0.f, s1=0.f, s2=0.f, s3=0.f, w=0.f;
        #pragma unroll
        for (int n = 0; n < NIN; n++){
            float a = actIn[n*J + t];
            const float* pb = &poseIn[(n*J + t)*4];
            s0 += a*pb[0]; s1 += a*pb[1]; s2 += a*pb[2]; s3 += a*pb[3];
            w += a;
        }
        float inv = 1.f/(sqrtf(s0*s0+s1*s1+s2*s2+s3*s3)+EPS);
        s0*=inv; s1*=inv; s2*=inv; s3*=inv;
        float ag = 0.f;
        #pragma unroll
        for (int n = 0; n < NIN; n++){
            float a = actIn[n*J + t];
            const float* pb = &poseIn[(n*J + t)*4];
            ag += a*(pb[0]*s0 + pb[1]*s1 + pb[2]*s2 + pb[3]*s3);
        }
        actOut[t] = sigmoidf_(ag / (w + EPS));
        poseOut[t*4+0]=s0; poseOut[t*4+1]=s1; poseOut[t*4+2]=s2; poseOut[t*4+3]=s3;
    } else if (t == J){
        float p0=0.f, p1=0.f, p2=0.f;
        #pragma unroll
        for (int n = 0; n < NIN; n++){
            p0 += posIn[n*3+0]; p1 += posIn[n*3+1]; p2 += posIn[n*3+2];
        }
        float c = (float)NIN + EPS;
        posOut[0]=p0/c; posOut[1]=p1/c; posOut[2]=p2/c;
    }
}

extern "C" void kernel_launch(void* const* d_in, const int* in_sizes, int n_in,
                              void* d_out, int out_size, void* d_ws, size_t ws_size,
                              hipStream_t stream){
    const float* x      = (const float*)d_in[0];
    const float* pos    = (const float*)d_in[1];
    const float* pseudo = (const float*)d_in[2];
    const float* Wsp    = (const float*)d_in[3];
    const float* root   = (const float*)d_in[4];
    const float* bias   = (const float*)d_in[5];
    const float* lin_w  = (const float*)d_in[6];
    const float* lin_b  = (const float*)d_in[7];
    const float* q0     = (const float*)d_in[8];
    const float* q1     = (const float*)d_in[9];
    const float* q3     = (const float*)d_in[10];
    const float* q5     = (const float*)d_in[11];
    const float* q6     = (const float*)d_in[12];
    const float* q7     = (const float*)d_in[13];
    const int*   ei     = (const int*)d_in[14];
    const int N = in_sizes[0];
    const int E = in_sizes[2] / 3;
    const int V1 = 32768;
    const int NB = (N + 255)/256;

    char* ws = (char*)d_ws;
    size_t off = 0;
    auto alloc = [&](size_t bytes)->void*{
        void* p = ws + off;
        off += (bytes + 255) & ~(size_t)255;
        return p;
    };
    unsigned* mm   = (unsigned*)alloc(8);
    int* deg       = (int*)alloc((size_t)N*sizeof(int));
    int* erank     = (int*)alloc((size_t)E*sizeof(int));
    int* eoff      = (int*)alloc((size_t)(N+1)*sizeof(int));
    int* bsum      = (int*)alloc((size_t)(NB+1)*sizeof(int));
    float4* rec4   = (float4*)alloc((size_t)E*sizeof(float4));
    int* recb      = (int*)alloc((size_t)E*sizeof(int));
    int* vhead     = (int*)alloc((size_t)V1*sizeof(int));
    int* vnxt      = (int*)alloc((size_t)N*sizeof(int));
    float* P0  = (float*)alloc((size_t)1250000*sizeof(float));
    float* P1  = (float*)alloc((size_t)1250000*sizeof(float));
    float* A0  = (float*)alloc((size_t)310000*sizeof(float));
    float* A1  = (float*)alloc((size_t)310000*sizeof(float));
    float* PB0 = (float*)alloc((size_t)100000*sizeof(float));
    float* PB1 = (float*)alloc((size_t)100000*sizeof(float));
    size_t pool_off0 = off;                     // shared pool scratch region
    float* vs  = (float*)alloc((size_t)512*8*4*sizeof(float));
    float* vw  = (float*)alloc((size_t)512*8*sizeof(float));
    float* va  = (float*)alloc((size_t)512*8*sizeof(float));
    float* vc  = (float*)alloc((size_t)512*sizeof(float));
    float* vp  = (float*)alloc((size_t)512*3*sizeof(float));
    size_t pool_bytes = off - pool_off0;

    hipMemsetAsync(mm,     0xFF, 4, stream);
    hipMemsetAsync(mm + 1, 0x00, 4, stream);
    hipMemsetAsync(deg, 0, (size_t)N*sizeof(int), stream);
    hipMemsetAsync(vhead, 0xFF, (size_t)V1*sizeof(int), stream);  // -1

    minmax_kernel<<<80, 256, 0, stream>>>(pos, N*3, mm);

    // CSR build: rank via atomicAdd, 3-kernel parallel scan, atomic-free scatter
    edge_rank<<<(E + 255)/256, 256, 0, stream>>>(ei, deg, erank, E);
    scan_bsum<<<NB, 256, 0, stream>>>(deg, bsum, N);
    scan_top<<<1, 1024, 0, stream>>>(bsum, NB);
    scan_final<<<NB, 256, 0, stream>>>(deg, bsum, eoff, N, NB);
    edge_pack<<<(E + 255)/256, 256, 0, stream>>>(ei, pseudo, x, erank, eoff, rec4, recb, E);
    spline_node_kernel<<<(8*N + 255)/256, 256, 0, stream>>>(x, rec4, recb, eoff, Wsp,
                                                            root, bias, lin_w, lin_b, P0, A0, N);

    // capsule layers: big-N -> per-node register kernels
    caps_node_kernel<1,6><<<(N + 63)/64, 64, 0, stream>>>(P0, A0, q0, P1, A1, N);
    caps_node_kernel<6,6><<<(N + 63)/64, 64, 0, stream>>>(P1, A1, q1, P0, A0, N);

    // pool1: 50000 -> 32768 voxels (G=32), J=6 — linked-list thread-per-voxel gather
    {
        const int G = 32;
        elist_node<<<(N + 255)/256, 256, 0, stream>>>(pos, vhead, vnxt, N, G, 0, mm);
        pool1_gather_kernel<6><<<(V1 + 255)/256, 256, 0, stream>>>(P0, A0, pos, vhead, vnxt,
                                                                   P1, A1, PB0, V1);
    }
    caps_node_kernel<6,8><<<(32768 + 63)/64, 64, 0, stream>>>(P1, A1, q3, P0, A0, 32768);

    // pool2: 32768 -> 512 (G=8), J=8 — node-parallel LDS-privatized, 64 slices
    {
        const int V = 512, J = 8, G = 8, NSL = 64;
        hipMemsetAsync(vs, 0, pool_bytes, stream);
        pool_priv1<V,J,4,2><<<2*NSL, 256, 0, stream>>>((const float4*)P0, A0, PB0,
                                                       vs, vw, vc, vp, 32768, G, 0, mm);
        pool_m<<<(V*J + 255)/256, 256, 0, stream>>>(vs, P1, V*J);
        pool_priv2<V,J><<<NSL, 256, 0, stream>>>((const float4*)P0, A0, PB0,
                                                 (const float4*)P1, va, 32768, G, 0, mm);
        pool_fin<<<(V*J + 255)/256, 256, 0, stream>>>(va, vw, vc, vp, A1, PB1, V, J);
    }
    caps_coop_kernel<8,12,2><<<256, 2*96, 0, stream>>>(P1, A1, q5, P0, A0, 512);

    // pool3: 512 -> 8 (G=2), J=12 — node-parallel privatized, 16 slices (proven path;
    // round-4's 1-block fused version serialized on same-address LDS atomics, 65us)
    {
        const int V = 8, J = 12, G = 2, NSL = 16;
        hipMemsetAsync(vs, 0, pool_bytes, stream);
        pool_priv1<V,J,12,1><<<NSL, 256, 0, stream>>>((const float4*)P0, A0, PB1,
                                                      vs, vw, vc, vp, 512, G, 0, mm);
        pool_m<<<1, 256, 0, stream>>>(vs, P1, V*J);
        pool_priv2<V,J><<<NSL, 256, 0, stream>>>((const float4*)P0, A0, PB1,
                                                 (const float4*)P1, va, 512, G, 0, mm);
        pool_fin<<<1, 256, 0, stream>>>(va, vw, vc, vp, A1, PB0, V, J);
    }
    caps_coop_kernel<12,14,1><<<8, 168, 0, stream>>>(P1, A1, q6, P0, A0, 8);

    // pool4: 8 -> 1 voxel — thread-per-capsule, no atomics
    pool4_tiny<8,14><<<1, 64, 0, stream>>>(P0, A0, PB0, P1, A1, PB1);
    caps_coop_kernel<14,10,1><<<1, 140, 0, stream>>>(P1, A1, q7, P0, (float*)d_out, 1);
}

// Round 6
// 332.471 us; speedup vs baseline: 1.5139x; 1.5139x over previous
//
#include <hip/hip_runtime.h>
#include <math.h>

#define EPS 1e-4f

__device__ __forceinline__ float sigmoidf_(float x){ return 1.0f/(1.0f+expf(-x)); }

// ---- ordered-uint mapping for float atomic min/max ----
__device__ __forceinline__ unsigned f2u_(float f){
    unsigned u = __float_as_uint(f);
    return (u & 0x80000000u) ? ~u : (u | 0x80000000u);
}
__device__ __forceinline__ float u2f_(unsigned u){
    unsigned b = (u & 0x80000000u) ? (u & 0x7FFFFFFFu) : ~u;
    return __uint_as_float(b);
}

// ================= min/max of pos =================
__global__ void minmax_kernel(const float* __restrict__ p, int n, unsigned* mm){
    float lo = INFINITY, hi = -INFINITY;
    for (int i = blockIdx.x*blockDim.x + threadIdx.x; i < n; i += gridDim.x*blockDim.x){
        float v = p[i]; lo = fminf(lo, v); hi = fmaxf(hi, v);
    }
    for (int off = 32; off > 0; off >>= 1){
        lo = fminf(lo, __shfl_down(lo, off));
        hi = fmaxf(hi, __shfl_down(hi, off));
    }
    __shared__ float slo[8], shi[8];
    int wid = threadIdx.x >> 6;
    if ((threadIdx.x & 63) == 0){ slo[wid] = lo; shi[wid] = hi; }
    __syncthreads();
    if (threadIdx.x == 0){
        int nw = blockDim.x >> 6;
        for (int w = 1; w < nw; w++){ lo = fminf(lo, slo[w]); hi = fmaxf(hi, shi[w]); }
        atomicMin(&mm[0], f2u_(lo));
        atomicMax(&mm[1], f2u_(hi));
    }
}

// ================= CSR build =================
__global__ void edge_rank(const int* __restrict__ ei, int* __restrict__ deg,
                          int* __restrict__ rank, int E){
    int e = blockIdx.x*blockDim.x + threadIdx.x;
    if (e >= E) return;
    rank[e] = atomicAdd(&deg[ei[E + e]], 1);
}

__global__ __launch_bounds__(256)
void scan_bsum(const int* __restrict__ deg, int* __restrict__ bsum, int N){
    int i = blockIdx.x*256 + threadIdx.x;
    int v = (i < N) ? deg[i] : 0;
    for (int o = 32; o > 0; o >>= 1) v += __shfl_down(v, o);
    __shared__ int ws[4];
    if ((threadIdx.x & 63) == 0) ws[threadIdx.x >> 6] = v;
    __syncthreads();
    if (threadIdx.x == 0) bsum[blockIdx.x] = ws[0] + ws[1] + ws[2] + ws[3];
}

__global__ __launch_bounds__(1024)
void scan_top(int* __restrict__ bsum, int NB){
    __shared__ int sh[1024];
    int t = threadIdx.x;
    int v = (t < NB) ? bsum[t] : 0;
    sh[t] = v;
    __syncthreads();
    for (int d = 1; d < 1024; d <<= 1){
        int u = (t >= d) ? sh[t - d] : 0;
        __syncthreads();
        sh[t] += u;
        __syncthreads();
    }
    if (t < NB) bsum[t] = sh[t] - v;
    if (t == 1023) bsum[NB] = sh[1023];
}

__global__ __launch_bounds__(256)
void scan_final(const int* __restrict__ deg, const int* __restrict__ bsum,
                int* __restrict__ off, int N, int NB){
    __shared__ int sh[256];
    int b = blockIdx.x;
    int i = b*256 + threadIdx.x;
    int v = (i < N) ? deg[i] : 0;
    sh[threadIdx.x] = v;
    __syncthreads();
    for (int d = 1; d < 256; d <<= 1){
        int u = (threadIdx.x >= d) ? sh[threadIdx.x - d] : 0;
        __syncthreads();
        sh[threadIdx.x] += u;
        __syncthreads();
    }
    if (i < N) off[i] = bsum[b] + sh[threadIdx.x] - v;    // exclusive
    if (b == 0 && threadIdx.x == 0) off[N] = bsum[NB];
}

// streaming pack + atomic-free scatter: slot = off[dst] + rank[e]
__global__ void edge_pack(const int* __restrict__ ei, const float* __restrict__ pseudo,
                          const float* __restrict__ x,
                          const int* __restrict__ rank, const int* __restrict__ off,
                          float4* __restrict__ rec4, int* __restrict__ recb, int E){
    int e = blockIdx.x*blockDim.x + threadIdx.x;
    if (e >= E) return;
    float p0 = pseudo[3*e], p1 = pseudo[3*e+1], p2 = pseudo[3*e+2];
    int s = ei[e], d = ei[E + e];
    float v0 = p0*4.f, v1 = p1*4.f, v2 = p2*4.f;
    float f0 = fminf(fmaxf(floorf(v0), 0.f), 3.f);
    float f1 = fminf(fmaxf(floorf(v1), 0.f), 3.f);
    float f2 = fminf(fmaxf(floorf(v2), 0.f), 3.f);
    int slot = off[d] + rank[e];
    rec4[slot] = make_float4(v0 - f0, v1 - f1, v2 - f2, x[s]);
    recb[slot] = ((int)f0*5 + (int)f1)*5 + (int)f2;
}

__device__ __forceinline__ int voxel_id(const float* __restrict__ pos, int n, int G,
                                        float start, float size){
    int g[3];
    #pragma unroll
    for (int k = 0; k < 3; k++){
        float gg = floorf((pos[(size_t)n*3 + k] - start) / size);
        gg = fminf(fmaxf(gg, 0.f), (float)(G - 1));
        g[k] = (int)gg;
    }
    return (g[0]*G + g[1])*G + g[2];
}

__device__ __forceinline__ void pool_geom(const unsigned* mm, int G, int mode,
                                          float& start, float& size){
    float mn = u2f_(mm[0]), mx = u2f_(mm[1]);
    if (mode == 0){ start = mn; size = (mx + 0.001f - mn) / (float)G; }
    else          { start = mn - 0.5f; size = mx - mn + 1.0f; }
}

__global__ void elist_node(const float* __restrict__ pos, int* __restrict__ head,
                           int* __restrict__ nxt, int N, int G, int mode,
                           const unsigned* __restrict__ mm){
    int n = blockIdx.x*blockDim.x + threadIdx.x;
    if (n >= N) return;
    float start, size; pool_geom(mm, G, mode, start, size);
    int v = voxel_id(pos, n, G, start, size);
    nxt[n] = atomicExch(&head[v], n);
}

// ===== fused spline gather + node finalize: 8 lanes per node (tid = n*8+k) =====
__global__ __launch_bounds__(256)
void spline_node_kernel(const float* __restrict__ x, const float4* __restrict__ rec4,
                        const int* __restrict__ recb, const int* __restrict__ off,
                        const float* __restrict__ W,
                        const float* __restrict__ root, const float* __restrict__ bias,
                        const float* __restrict__ lin_w, const float* __restrict__ lin_b,
                        float* __restrict__ pose, float* __restrict__ act, int N){
    __shared__ float Ws[125*17];
    for (int i = threadIdx.x; i < 125*16; i += blockDim.x)
        Ws[(i >> 4)*17 + (i & 15)] = W[i];
    __syncthreads();
    int t = blockIdx.x*blockDim.x + threadIdx.x;
    int n = t >> 3;
    int k = t & 7;
    if (n >= N) return;     // group-uniform guard (all 8 lanes share n)

    int o0 = off[n], o1 = off[n+1];

    float agg[16];
    #pragma unroll
    for (int o = 0; o < 16; o++) agg[o] = 0.f;

    for (int s = o0 + k; s < o1; s += 8){
        float4 rv = rec4[s];
        int base = recb[s];
        float fr0 = rv.x, fr1 = rv.y, fr2 = rv.z, xv = rv.w;
        #pragma unroll
        for (int b = 0; b < 8; b++){
            int b0 = (b >> 2) & 1, b1 = (b >> 1) & 1, b2 = b & 1;
            float w = (b0 ? fr0 : 1.f - fr0) * (b1 ? fr1 : 1.f - fr1) * (b2 ? fr2 : 1.f - fr2);
            w *= xv;
            const float* Wr = &Ws[(base + b0*25 + b1*5 + b2)*17];
            #pragma unroll
            for (int o = 0; o < 16; o++) agg[o] += w * Wr[o];
        }
    }

    // 8-lane reduction (lanes n*8..n*8+7)
    #pragma unroll
    for (int o = 0; o < 16; o++){
        agg[o] += __shfl_xor(agg[o], 1);
        agg[o] += __shfl_xor(agg[o], 2);
        agg[o] += __shfl_xor(agg[o], 4);
    }

    if (k != 0) return;

    float deg = fmaxf((float)(o1 - o0), 1.0f);
    float xs = x[n];
    float qv0 = lin_b[0], qv1 = lin_b[1], qv2 = lin_b[2], qv3 = lin_b[3];
    #pragma unroll
    for (int o = 0; o < 16; o++){
        float h = agg[o] / deg + xs * root[o] + bias[o];
        float e = (h > 0.f) ? h : expm1f(h);
        qv0 += e * lin_w[o*4 + 0];
        qv1 += e * lin_w[o*4 + 1];
        qv2 += e * lin_w[o*4 + 2];
        qv3 += e * lin_w[o*4 + 3];
    }
    float inv = 1.0f / (sqrtf(qv0*qv0 + qv1*qv1 + qv2*qv2 + qv3*qv3) + EPS);
    pose[(size_t)n*4 + 0] = qv0*inv;
    pose[(size_t)n*4 + 1] = qv1*inv;
    pose[(size_t)n*4 + 2] = qv2*inv;
    pose[(size_t)n*4 + 3] = qv3*inv;
    act[n] = xs;
}

// ====== capsule routing — wave-level, 8 lanes per node (big-N layers, J<=8) ======
// Round-5 evidence: thread-per-node caps spilled (208 VGPR, 5.5% occupancy, ~105us).
// Decompose by output capsule j: lane j of an 8-lane group holds pr[i][4], b[i], c[i]
// (<=40 floats). v[j] and the b-update are LANE-LOCAL (sums over i). Only the softmax
// over j crosses lanes: 3x shfl_xor (masks 1,2,4 stay in the 8-lane group). Zero LDS
// in the loop, zero barriers, ~60 VGPR -> full occupancy.
template<int I, int J>
__global__ __launch_bounds__(256)
void caps_wave_kernel(const float* __restrict__ poseIn, const float* __restrict__ actIn,
                      const float* __restrict__ q,
                      float* __restrict__ poseOut, float* __restrict__ actOut, int N){
    __shared__ float qn[I*J*4];
    for (int t = threadIdx.x; t < I*J; t += blockDim.x){
        float qa=q[t*4], qb=q[t*4+1], qc=q[t*4+2], qd=q[t*4+3];
        float inv = 1.f/(sqrtf(qa*qa+qb*qb+qc*qc+qd*qd)+EPS);
        qn[t*4+0]=qa*inv; qn[t*4+1]=qb*inv; qn[t*4+2]=qc*inv; qn[t*4+3]=qd*inv;
    }
    __syncthreads();
    int tid = blockIdx.x*blockDim.x + threadIdx.x;
    int n = tid >> 3;
    int j = tid & 7;
    const bool on = (n < N) && (j < J);

    float pr[I][4], a[I], b[I];
    #pragma unroll
    for (int i = 0; i < I; i++){
        pr[i][0]=pr[i][1]=pr[i][2]=pr[i][3]=0.f; a[i]=0.f;
        b[i] = on ? 0.f : -INFINITY;       // inactive lanes never win max, e=0
    }
    if (on){
        #pragma unroll
        for (int i = 0; i < I; i++){
            float4 p = *reinterpret_cast<const float4*>(&poseIn[((size_t)n*I + i)*4]);
            a[i] = actIn[(size_t)n*I + i];
            const float* qq = &qn[(i*J + j)*4];
            float qx=qq[0], qy=qq[1], qz=qq[2], qw=qq[3];
            float tx = qw*p.x + qx*p.w + qy*p.z - qz*p.y;
            float ty = qw*p.y - qx*p.z + qy*p.w + qz*p.x;
            float tz = qw*p.z + qx*p.y - qy*p.x + qz*p.w;
            float tw = qw*p.w - qx*p.x - qy*p.y - qz*p.z;
            float inv = 1.f/(sqrtf(tx*tx+ty*ty+tz*tz+tw*tw)+EPS);
            pr[i][0]=tx*inv; pr[i][1]=ty*inv; pr[i][2]=tz*inv; pr[i][3]=tw*inv;
        }
    }

    float c[I], v0=0.f, v1=0.f, v2=0.f, v3=0.f;
    #pragma unroll
    for (int t = 0; t < 3; t++){
        #pragma unroll
        for (int i = 0; i < I; i++){
            float mb = b[i];
            mb = fmaxf(mb, __shfl_xor(mb, 1));
            mb = fmaxf(mb, __shfl_xor(mb, 2));
            mb = fmaxf(mb, __shfl_xor(mb, 4));
            float e = on ? expf(b[i] - mb) : 0.f;
            float s = e;
            s += __shfl_xor(s, 1);
            s += __shfl_xor(s, 2);
            s += __shfl_xor(s, 4);
            c[i] = a[i] * e / s;           // s>0 whenever the group has active lanes
        }
        float s0=0.f, s1=0.f, s2=0.f, s3=0.f;
        #pragma unroll
        for (int i = 0; i < I; i++){
            s0 += c[i]*pr[i][0]; s1 += c[i]*pr[i][1];
            s2 += c[i]*pr[i][2]; s3 += c[i]*pr[i][3];
        }
        float inv = 1.f/(sqrtf(s0*s0+s1*s1+s2*s2+s3*s3)+EPS);
        v0=s0*inv; v1=s1*inv; v2=s2*inv; v3=s3*inv;
        if (t < 2){
            #pragma unroll
            for (int i = 0; i < I; i++)
                b[i] += pr[i][0]*v0 + pr[i][1]*v1 + pr[i][2]*v2 + pr[i][3]*v3;
        }
    }

    if (on){
        float acc = 0.f;
        #pragma unroll
        for (int i = 0; i < I; i++)
            acc += c[i]*(pr[i][0]*v0 + pr[i][1]*v1 + pr[i][2]*v2 + pr[i][3]*v3);
        actOut[(size_t)n*J + j] = sigmoidf_(acc);
        *reinterpret_cast<float4*>(&poseOut[((size_t)n*J + j)*4]) =
            make_float4(v0, v1, v2, v3);
    }
}

// ====== capsule routing — cooperative (small-N tail layers) ======
template<int I, int J, int NPB>
__global__ __launch_bounds__(NPB*I*J)
void caps_coop_kernel(const float* __restrict__ poseIn, const float* __restrict__ actIn,
                      const float* __restrict__ q, float* __restrict__ poseOut,
                      float* __restrict__ actOut, int N){
    const int IJ = I*J;
    const int tid = threadIdx.x;
    const int nl  = tid / IJ;
    const int li  = tid - nl*IJ;
    const int i   = li / J;
    const int j   = li - i*J;
    const int node = blockIdx.x*NPB + nl;
    const bool on = (node < N);

    __shared__ float redA[NPB][I*J];
    __shared__ float redB[NPB][I*J];
    __shared__ float cp[NPB][I*J*4];
    __shared__ float vsh[NPB][J*4];

    float prx=0.f, pry=0.f, prz=0.f, prw=0.f, ai=0.f;
    if (on){
        float qx = q[li*4+0], qy = q[li*4+1], qz = q[li*4+2], qw = q[li*4+3];
        float qinv = 1.0f/(sqrtf(qx*qx+qy*qy+qz*qz+qw*qw)+EPS);
        qx*=qinv; qy*=qinv; qz*=qinv; qw*=qinv;
        const float* pp = &poseIn[((size_t)node*I + i)*4];
        float rx=pp[0], ry=pp[1], rz=pp[2], rw=pp[3];
        ai = actIn[(size_t)node*I + i];
        float tx = qw*rx + qx*rw + qy*rz - qz*ry;
        float ty = qw*ry - qx*rz + qy*rw + qz*rx;
        float tz = qw*rz + qx*ry - qy*rx + qz*rw;
        float tw = qw*rw - qx*rx - qy*ry - qz*rz;
        float pinv = 1.0f/(sqrtf(tx*tx+ty*ty+tz*tz+tw*tw)+EPS);
        prx=tx*pinv; pry=ty*pinv; prz=tz*pinv; prw=tw*pinv;
    }

    float b = 0.f, c = 0.f;
    for (int t = 0; t < 3; t++){
        redA[nl][li] = b;
        __syncthreads();
        float mb = -INFINITY;
        #pragma unroll
        for (int jj = 0; jj < J; jj++) mb = fmaxf(mb, redA[nl][i*J+jj]);
        float e = expf(b - mb);
        redB[nl][li] = e;
        __syncthreads();
        float s = 0.f;
        #pragma unroll
        for (int jj = 0; jj < J; jj++) s += redB[nl][i*J+jj];
        c = ai * e / s;
        cp[nl][li*4+0] = c*prx; cp[nl][li*4+1] = c*pry;
        cp[nl][li*4+2] = c*prz; cp[nl][li*4+3] = c*prw;
        __syncthreads();
        for (int idx = li; idx < J*4; idx += IJ){
            int jj = idx >> 2, comp = idx & 3;
            float acc = 0.f;
            #pragma unroll
            for (int ii = 0; ii < I; ii++) acc += cp[nl][(ii*J+jj)*4+comp];
            vsh[nl][idx] = acc;
        }
        __syncthreads();
        if (li < J){
            float a0=vsh[nl][li*4], a1=vsh[nl][li*4+1], a2=vsh[nl][li*4+2], a3=vsh[nl][li*4+3];
            float inv = 1.0f/(sqrtf(a0*a0+a1*a1+a2*a2+a3*a3)+EPS);
            vsh[nl][li*4]=a0*inv; vsh[nl][li*4+1]=a1*inv;
            vsh[nl][li*4+2]=a2*inv; vsh[nl][li*4+3]=a3*inv;
        }
        __syncthreads();
        if (t < 2){
            b += prx*vsh[nl][j*4] + pry*vsh[nl][j*4+1] + prz*vsh[nl][j*4+2] + prw*vsh[nl][j*4+3];
            __syncthreads();
        } else {
            redA[nl][li] = c*(prx*vsh[nl][j*4] + pry*vsh[nl][j*4+1]
                            + prz*vsh[nl][j*4+2] + prw*vsh[nl][j*4+3]);
            __syncthreads();
            if (li < J && on){
                float acc = 0.f;
                #pragma unroll
                for (int ii = 0; ii < I; ii++) acc += redA[nl][ii*J+li];
                actOut[(size_t)node*J + li] = sigmoidf_(acc);
                poseOut[((size_t)node*J+li)*4+0] = vsh[nl][li*4+0];
                poseOut[((size_t)node*J+li)*4+1] = vsh[nl][li*4+1];
                poseOut[((size_t)node*J+li)*4+2] = vsh[nl][li*4+2];
                poseOut[((size_t)node*J+li)*4+3] = vsh[nl][li*4+3];
            }
        }
    }
}

// ---------- pool1 (V=32768, ~1.5 nodes/voxel): thread-per-voxel linked-list gather ----------
template<int J>
__global__ __launch_bounds__(256)
void pool1_gather_kernel(const float* __restrict__ pose, const float* __restrict__ act,
                         const float* __restrict__ pos,
                         const int* __restrict__ head, const int* __restrict__ nxt,
                         float* __restrict__ poseOut, float* __restrict__ actOut,
                         float* __restrict__ posOut, int V){
    int v = blockIdx.x*blockDim.x + threadIdx.x;
    if (v >= V) return;

    float s[J][4], w[J], ps0=0.f, ps1=0.f, ps2=0.f;
    #pragma unroll
    for (int j = 0; j < J; j++){ s[j][0]=0.f; s[j][1]=0.f; s[j][2]=0.f; s[j][3]=0.f; w[j]=0.f; }

    int cnt = 0;
    for (int n = head[v]; n >= 0; n = nxt[n]){
        const float* pb = &pose[(size_t)n*J*4];
        const float* ab = &act[(size_t)n*J];
        #pragma unroll
        for (int j = 0; j < J; j++){
            float aj = ab[j];
            s[j][0] += aj*pb[j*4+0];
            s[j][1] += aj*pb[j*4+1];
            s[j][2] += aj*pb[j*4+2];
            s[j][3] += aj*pb[j*4+3];
            w[j] += aj;
        }
        ps0 += pos[(size_t)n*3+0];
        ps1 += pos[(size_t)n*3+1];
        ps2 += pos[(size_t)n*3+2];
        cnt++;
    }
    #pragma unroll
    for (int j = 0; j < J; j++){
        float inv = 1.0f/(sqrtf(s[j][0]*s[j][0]+s[j][1]*s[j][1]+
                                s[j][2]*s[j][2]+s[j][3]*s[j][3])+EPS);
        s[j][0]*=inv; s[j][1]*=inv; s[j][2]*=inv; s[j][3]*=inv;
    }
    float ag[J];
    #pragma unroll
    for (int j = 0; j < J; j++) ag[j] = 0.f;
    for (int n = head[v]; n >= 0; n = nxt[n]){
        const float* pb = &pose[(size_t)n*J*4];
        const float* ab = &act[(size_t)n*J];
        #pragma unroll
        for (int j = 0; j < J; j++){
            float agree = pb[j*4+0]*s[j][0] + pb[j*4+1]*s[j][1]
                        + pb[j*4+2]*s[j][2] + pb[j*4+3]*s[j][3];
            ag[j] += ab[j]*agree;
        }
    }
    #pragma unroll
    for (int j = 0; j < J; j++){
        size_t o = (size_t)v*J + j;
        actOut[o] = sigmoidf_(ag[j] / (w[j] + EPS));
        poseOut[o*4+0] = s[j][0];
        poseOut[o*4+1] = s[j][1];
        poseOut[o*4+2] = s[j][2];
        poseOut[o*4+3] = s[j][3];
    }
    float c = (float)cnt + EPS;
    posOut[(size_t)v*3+0] = ps0 / c;
    posOut[(size_t)v*3+1] = ps1 / c;
    posOut[(size_t)v*3+2] = ps2 / c;
}

// ---------- pools 2-3 (small V, heavy skew): node-parallel LDS-privatized ----------
template<int V, int J, int CH, int NCHUNK>
__global__ void pool_priv1(const float4* __restrict__ poseIn, const float* __restrict__ actIn,
                           const float* __restrict__ posIn,
                           float* __restrict__ s, float* __restrict__ wsum,
                           float* __restrict__ cnt, float* __restrict__ psum,
                           int N, int G, int mode, const unsigned* __restrict__ mm){
    __shared__ float s_[V*CH*4];
    __shared__ float wsum_[V*CH];
    __shared__ float cnt_[V];
    __shared__ float psum_[V*3];
    const int chunk = blockIdx.x % NCHUNK;
    const int slice = blockIdx.x / NCHUNK;
    const int nslices = gridDim.x / NCHUNK;
    const int c0 = chunk * CH;

    for (int t = threadIdx.x; t < V*CH*4; t += blockDim.x) s_[t] = 0.f;
    for (int t = threadIdx.x; t < V*CH; t += blockDim.x) wsum_[t] = 0.f;
    if (chunk == 0){
        for (int t = threadIdx.x; t < V; t += blockDim.x) cnt_[t] = 0.f;
        for (int t = threadIdx.x; t < V*3; t += blockDim.x) psum_[t] = 0.f;
    }
    __syncthreads();

    float start, size; pool_geom(mm, G, mode, start, size);
    int per = (N + nslices - 1) / nslices;
    int n0 = slice * per, n1 = min(N, n0 + per);

    for (int n = n0 + (int)threadIdx.x; n < n1; n += blockDim.x){
        int vid = voxel_id(posIn, n, G, start, size);
        #pragma unroll
        for (int jj = 0; jj < CH; jj++){
            int j = c0 + jj;
            float aj = actIn[(size_t)n*J + j];
            float4 p = poseIn[(size_t)n*J + j];
            int b = (vid*CH + jj)*4;
            atomicAdd(&s_[b+0], aj*p.x);
            atomicAdd(&s_[b+1], aj*p.y);
            atomicAdd(&s_[b+2], aj*p.z);
            atomicAdd(&s_[b+3], aj*p.w);
            atomicAdd(&wsum_[vid*CH + jj], aj);
        }
        if (chunk == 0){
            atomicAdd(&cnt_[vid], 1.0f);
            atomicAdd(&psum_[vid*3+0], posIn[(size_t)n*3+0]);
            atomicAdd(&psum_[vid*3+1], posIn[(size_t)n*3+1]);
            atomicAdd(&psum_[vid*3+2], posIn[(size_t)n*3+2]);
        }
    }
    __syncthreads();

    for (int t = threadIdx.x; t < V*CH*4; t += blockDim.x){
        float val = s_[t];
        if (val != 0.f){
            int v = t / (CH*4), r = t % (CH*4);
            atomicAdd(&s[((size_t)v*J + c0)*4 + r], val);
        }
    }
    for (int t = threadIdx.x; t < V*CH; t += blockDim.x){
        float val = wsum_[t];
        if (val != 0.f){
            int v = t / CH, jj = t % CH;
            atomicAdd(&wsum[(size_t)v*J + c0 + jj], val);
        }
    }
    if (chunk == 0){
        for (int t = threadIdx.x; t < V; t += blockDim.x)
            if (cnt_[t] != 0.f) atomicAdd(&cnt[t], cnt_[t]);
        for (int t = threadIdx.x; t < V*3; t += blockDim.x)
            if (psum_[t] != 0.f) atomicAdd(&psum[t], psum_[t]);
    }
}

template<int V, int J>
__global__ void pool_priv2(const float4* __restrict__ poseIn, const float* __restrict__ actIn,
                           const float* __restrict__ posIn, const float4* __restrict__ m,
                           float* __restrict__ agacc,
                           int N, int G, int mode, const unsigned* __restrict__ mm){
    __shared__ float ag_[V*J];
    for (int t = threadIdx.x; t < V*J; t += blockDim.x) ag_[t] = 0.f;
    __syncthreads();
    float start, size; pool_geom(mm, G, mode, start, size);
    int nslices = gridDim.x;
    int per = (N + nslices - 1) / nslices;
    int n0 = blockIdx.x * per, n1 = min(N, n0 + per);
    for (int n = n0 + (int)threadIdx.x; n < n1; n += blockDim.x){
        int vid = voxel_id(posIn, n, G, start, size);
        #pragma unroll
        for (int j = 0; j < J; j++){
            float4 p  = poseIn[(size_t)n*J + j];
            float4 mv = m[(size_t)vid*J + j];
            float agree = p.x*mv.x + p.y*mv.y + p.z*mv.z + p.w*mv.w;
            atomicAdd(&ag_[vid*J + j], actIn[(size_t)n*J + j]*agree);
        }
    }
    __syncthreads();
    for (int t = threadIdx.x; t < V*J; t += blockDim.x)
        if (ag_[t] != 0.f) atomicAdd(&agacc[t], ag_[t]);
}

__global__ void pool_m(const float* __restrict__ s, float* __restrict__ m, int VJ){
    int t = blockIdx.x*blockDim.x + threadIdx.x;
    if (t >= VJ) return;
    float a = s[(size_t)t*4], b = s[(size_t)t*4+1], c = s[(size_t)t*4+2], d = s[(size_t)t*4+3];
    float inv = 1.0f / (sqrtf(a*a + b*b + c*c + d*d) + EPS);
    m[(size_t)t*4]   = a*inv;
    m[(size_t)t*4+1] = b*inv;
    m[(size_t)t*4+2] = c*inv;
    m[(size_t)t*4+3] = d*inv;
}

__global__ void pool_fin(const float* __restrict__ agacc, const float* __restrict__ wsum,
                         const float* __restrict__ cnt, const float* __restrict__ psum,
                         float* __restrict__ actOut, float* __restrict__ posOut, int V, int J){
    int t = blockIdx.x*blockDim.x + threadIdx.x;
    if (t >= V*J) return;
    int v = t / J, j = t % J;
    actOut[t] = sigmoidf_(agacc[t] / (wsum[t] + EPS));
    if (j == 0){
        float c = cnt[v] + EPS;
        posOut[(size_t)v*3 + 0] = psum[(size_t)v*3 + 0] / c;
        posOut[(size_t)v*3 + 1] = psum[(size_t)v*3 + 1] / c;
        posOut[(size_t)v*3 + 2] = psum[(size_t)v*3 + 2] / c;
    }
}

// ---------- pool4 (NIN=8 -> V=1): thread-per-capsule, zero atomics ----------
template<int NIN, int J>
__global__ __launch_bounds__(64)
void pool4_tiny(const float* __restrict__ poseIn, const float* __restrict__ actIn,
                const float* __restrict__ posIn,
                float* __restrict__ poseOut, float* __restrict__ actOut,
                float* __restrict__ posOut){
    int t = threadIdx.x;
    if (t < J){
        float s0=0.f, s1=0.f, s2=0.f, s3=0.f, w=0.f;
        #pragma unroll
        for (int n = 0; n < NIN; n++){
            float a = actIn[n*J + t];
            const float* pb = &poseIn[(n*J + t)*4];
            s0 += a*pb[0]; s1 += a*pb[1]; s2 += a*pb[2]; s3 += a*pb[3];
            w += a;
        }
        float inv = 1.f/(sqrtf(s0*s0+s1*s1+s2*s2+s3*s3)+EPS);
        s0*=inv; s1*=inv; s2*=inv; s3*=inv;
        float ag = 0.f;
        #pragma unroll
        for (int n = 0; n < NIN; n++){
            float a = actIn[n*J + t];
            const float* pb = &poseIn[(n*J + t)*4];
            ag += a*(pb[0]*s0 + pb[1]*s1 + pb[2]*s2 + pb[3]*s3);
        }
        actOut[t] = sigmoidf_(ag / (w + EPS));
        poseOut[t*4+0]=s0; poseOut[t*4+1]=s1; poseOut[t*4+2]=s2; poseOut[t*4+3]=s3;
    } else if (t == J){
        float p0=0.f, p1=0.f, p2=0.f;
        #pragma unroll
        for (int n = 0; n < NIN; n++){
            p0 += posIn[n*3+0]; p1 += posIn[n*3+1]; p2 += posIn[n*3+2];
        }
        float c = (float)NIN + EPS;
        posOut[0]=p0/c; posOut[1]=p1/c; posOut[2]=p2/c;
    }
}

extern "C" void kernel_launch(void* const* d_in, const int* in_sizes, int n_in,
                              void* d_out, int out_size, void* d_ws, size_t ws_size,
                              hipStream_t stream){
    const float* x      = (const float*)d_in[0];
    const float* pos    = (const float*)d_in[1];
    const float* pseudo = (const float*)d_in[2];
    const float* Wsp    = (const float*)d_in[3];
    const float* root   = (const float*)d_in[4];
    const float* bias   = (const float*)d_in[5];
    const float* lin_w  = (const float*)d_in[6];
    const float* lin_b  = (const float*)d_in[7];
    const float* q0     = (const float*)d_in[8];
    const float* q1     = (const float*)d_in[9];
    const float* q3     = (const float*)d_in[10];
    const float* q5     = (const float*)d_in[11];
    const float* q6     = (const float*)d_in[12];
    const float* q7     = (const float*)d_in[13];
    const int*   ei     = (const int*)d_in[14];
    const int N = in_sizes[0];
    const int E = in_sizes[2] / 3;
    const int V1 = 32768;
    const int NB = (N + 255)/256;

    char* ws = (char*)d_ws;
    size_t off = 0;
    auto alloc = [&](size_t bytes)->void*{
        void* p = ws + off;
        off += (bytes + 255) & ~(size_t)255;
        return p;
    };
    unsigned* mm   = (unsigned*)alloc(8);
    int* deg       = (int*)alloc((size_t)N*sizeof(int));
    int* erank     = (int*)alloc((size_t)E*sizeof(int));
    int* eoff      = (int*)alloc((size_t)(N+1)*sizeof(int));
    int* bsum      = (int*)alloc((size_t)(NB+1)*sizeof(int));
    float4* rec4   = (float4*)alloc((size_t)E*sizeof(float4));
    int* recb      = (int*)alloc((size_t)E*sizeof(int));
    int* vhead     = (int*)alloc((size_t)V1*sizeof(int));
    int* vnxt      = (int*)alloc((size_t)N*sizeof(int));
    float* P0  = (float*)alloc((size_t)1250000*sizeof(float));
    float* P1  = (float*)alloc((size_t)1250000*sizeof(float));
    float* A0  = (float*)alloc((size_t)310000*sizeof(float));
    float* A1  = (float*)alloc((size_t)310000*sizeof(float));
    float* PB0 = (float*)alloc((size_t)100000*sizeof(float));
    float* PB1 = (float*)alloc((size_t)100000*sizeof(float));
    size_t pool_off0 = off;                     // shared pool scratch region
    float* vs  = (float*)alloc((size_t)512*8*4*sizeof(float));
    float* vw  = (float*)alloc((size_t)512*8*sizeof(float));
    float* va  = (float*)alloc((size_t)512*8*sizeof(float));
    float* vc  = (float*)alloc((size_t)512*sizeof(float));
    float* vp  = (float*)alloc((size_t)512*3*sizeof(float));
    size_t pool_bytes = off - pool_off0;

    hipMemsetAsync(mm,     0xFF, 4, stream);
    hipMemsetAsync(mm + 1, 0x00, 4, stream);
    hipMemsetAsync(deg, 0, (size_t)N*sizeof(int), stream);
    hipMemsetAsync(vhead, 0xFF, (size_t)V1*sizeof(int), stream);  // -1

    minmax_kernel<<<80, 256, 0, stream>>>(pos, N*3, mm);

    // CSR build: rank via atomicAdd, 3-kernel parallel scan, atomic-free scatter
    edge_rank<<<(E + 255)/256, 256, 0, stream>>>(ei, deg, erank, E);
    scan_bsum<<<NB, 256, 0, stream>>>(deg, bsum, N);
    scan_top<<<1, 1024, 0, stream>>>(bsum, NB);
    scan_final<<<NB, 256, 0, stream>>>(deg, bsum, eoff, N, NB);
    edge_pack<<<(E + 255)/256, 256, 0, stream>>>(ei, pseudo, x, erank, eoff, rec4, recb, E);
    spline_node_kernel<<<(8*N + 255)/256, 256, 0, stream>>>(x, rec4, recb, eoff, Wsp,
                                                            root, bias, lin_w, lin_b, P0, A0, N);

    // capsule layers: big-N -> wave-level (8 lanes/node, shfl softmax)
    caps_wave_kernel<1,6><<<(8*N + 255)/256, 256, 0, stream>>>(P0, A0, q0, P1, A1, N);
    caps_wave_kernel<6,6><<<(8*N + 255)/256, 256, 0, stream>>>(P1, A1, q1, P0, A0, N);

    // pool1: 50000 -> 32768 voxels (G=32), J=6 — linked-list thread-per-voxel gather
    {
        const int G = 32;
        elist_node<<<(N + 255)/256, 256, 0, stream>>>(pos, vhead, vnxt, N, G, 0, mm);
        pool1_gather_kernel<6><<<(V1 + 255)/256, 256, 0, stream>>>(P0, A0, pos, vhead, vnxt,
                                                                   P1, A1, PB0, V1);
    }
    caps_wave_kernel<6,8><<<(8*32768 + 255)/256, 256, 0, stream>>>(P1, A1, q3, P0, A0, 32768);

    // pool2: 32768 -> 512 (G=8), J=8 — node-parallel LDS-privatized, 64 slices
    {
        const int V = 512, J = 8, G = 8, NSL = 64;
        hipMemsetAsync(vs, 0, pool_bytes, stream);
        pool_priv1<V,J,4,2><<<2*NSL, 256, 0, stream>>>((const float4*)P0, A0, PB0,
                                                       vs, vw, vc, vp, 32768, G, 0, mm);
        pool_m<<<(V*J + 255)/256, 256, 0, stream>>>(vs, P1, V*J);
        pool_priv2<V,J><<<NSL, 256, 0, stream>>>((const float4*)P0, A0, PB0,
                                                 (const float4*)P1, va, 32768, G, 0, mm);
        pool_fin<<<(V*J + 255)/256, 256, 0, stream>>>(va, vw, vc, vp, A1, PB1, V, J);
    }
    caps_coop_kernel<8,12,2><<<256, 2*96, 0, stream>>>(P1, A1, q5, P0, A0, 512);

    // pool3: 512 -> 8 (G=2), J=12 — node-parallel privatized, 16 slices
    {
        const int V = 8, J = 12, G = 2, NSL = 16;
        hipMemsetAsync(vs, 0, pool_bytes, stream);
        pool_priv1<V,J,12,1><<<NSL, 256, 0, stream>>>((const float4*)P0, A0, PB1,
                                                      vs, vw, vc, vp, 512, G, 0, mm);
        pool_m<<<1, 256, 0, stream>>>(vs, P1, V*J);
        pool_priv2<V,J><<<NSL, 256, 0, stream>>>((const float4*)P0, A0, PB1,
                                                 (const float4*)P1, va, 512, G, 0, mm);
        pool_fin<<<1, 256, 0, stream>>>(va, vw, vc, vp, A1, PB0, V, J);
    }
    caps_coop_kernel<12,14,1><<<8, 168, 0, stream>>>(P1, A1, q6, P0, A0, 8);

    // pool4: 8 -> 1 voxel — thread-per-capsule, no atomics
    pool4_tiny<8,14><<<1, 64, 0, stream>>>(P0, A0, PB0, P1, A1, PB1);
    caps_coop_kernel<14,10,1><<<1, 140, 0, stream>>>(P1, A1, q7, P0, (float*)d_out, 1);
}

// Round 8
// 309.315 us; speedup vs baseline: 1.6273x; 1.0749x over previous
//
#include <hip/hip_runtime.h>
#include <math.h>

#define EPS 1e-4f

__device__ __forceinline__ float sigmoidf_(float x){ return 1.0f/(1.0f+expf(-x)); }

// ---- ordered-uint mapping for float atomic min/max ----
__device__ __forceinline__ unsigned f2u_(float f){
    unsigned u = __float_as_uint(f);
    return (u & 0x80000000u) ? ~u : (u | 0x80000000u);
}
__device__ __forceinline__ float u2f_(unsigned u){
    unsigned b = (u & 0x80000000u) ? (u & 0x7FFFFFFFu) : ~u;
    return __uint_as_float(b);
}

// ================= init: all memsets in one launch =================
__global__ void init_kernel(unsigned* __restrict__ mm, int* __restrict__ deg, int N,
                            int* __restrict__ vhead, int V,
                            float* __restrict__ pz, int PZ){
    int i = blockIdx.x*blockDim.x + threadIdx.x;
    int stride = gridDim.x*blockDim.x;
    if (i == 0){ mm[0] = 0xFFFFFFFFu; mm[1] = 0u; }
    for (int t = i; t < N; t += stride) deg[t] = 0;
    for (int t = i; t < V; t += stride) vhead[t] = -1;
    for (int t = i; t < PZ; t += stride) pz[t] = 0.f;
}

// ================= prep: minmax(pos) + edge_rank fused (independent outputs) ==========
__global__ void prep_kernel(const float* __restrict__ p, int n3, unsigned* mm,
                            const int* __restrict__ ei, int* __restrict__ deg,
                            int* __restrict__ rank, int E){
    int gid = blockIdx.x*blockDim.x + threadIdx.x;
    int stride = gridDim.x*blockDim.x;
    float lo = INFINITY, hi = -INFINITY;
    for (int i = gid; i < n3; i += stride){
        float v = p[i]; lo = fminf(lo, v); hi = fmaxf(hi, v);
    }
    for (int off = 32; off > 0; off >>= 1){
        lo = fminf(lo, __shfl_down(lo, off));
        hi = fmaxf(hi, __shfl_down(hi, off));
    }
    __shared__ float slo[4], shi[4];
    int wid = threadIdx.x >> 6;
    if ((threadIdx.x & 63) == 0){ slo[wid] = lo; shi[wid] = hi; }
    __syncthreads();
    if (threadIdx.x == 0){
        for (int w = 1; w < 4; w++){ lo = fminf(lo, slo[w]); hi = fmaxf(hi, shi[w]); }
        atomicMin(&mm[0], f2u_(lo));
        atomicMax(&mm[1], f2u_(hi));
    }
    for (int e = gid; e < E; e += stride)
        rank[e] = atomicAdd(&deg[ei[E + e]], 1);
}

// ================= CSR scan (3-kernel parallel, proven in R3) =================
__global__ __launch_bounds__(256)
void scan_bsum(const int* __restrict__ deg, int* __restrict__ bsum, int N){
    int i = blockIdx.x*256 + threadIdx.x;
    int v = (i < N) ? deg[i] : 0;
    for (int o = 32; o > 0; o >>= 1) v += __shfl_down(v, o);
    __shared__ int ws[4];
    if ((threadIdx.x & 63) == 0) ws[threadIdx.x >> 6] = v;
    __syncthreads();
    if (threadIdx.x == 0) bsum[blockIdx.x] = ws[0] + ws[1] + ws[2] + ws[3];
}

__global__ __launch_bounds__(1024)
void scan_top(int* __restrict__ bsum, int NB){
    __shared__ int sh[1024];
    int t = threadIdx.x;
    int v = (t < NB) ? bsum[t] : 0;
    sh[t] = v;
    __syncthreads();
    for (int d = 1; d < 1024; d <<= 1){
        int u = (t >= d) ? sh[t - d] : 0;
        __syncthreads();
        sh[t] += u;
        __syncthreads();
    }
    if (t < NB) bsum[t] = sh[t] - v;
    if (t == 1023) bsum[NB] = sh[1023];
}

__global__ __launch_bounds__(256)
void scan_final(const int* __restrict__ deg, const int* __restrict__ bsum,
                int* __restrict__ off, int N, int NB){
    __shared__ int sh[256];
    int b = blockIdx.x;
    int i = b*256 + threadIdx.x;
    int v = (i < N) ? deg[i] : 0;
    sh[threadIdx.x] = v;
    __syncthreads();
    for (int d = 1; d < 256; d <<= 1){
        int u = (threadIdx.x >= d) ? sh[threadIdx.x - d] : 0;
        __syncthreads();
        sh[threadIdx.x] += u;
        __syncthreads();
    }
    if (i < N) off[i] = bsum[b] + sh[threadIdx.x] - v;    // exclusive
    if (b == 0 && threadIdx.x == 0) off[N] = bsum[NB];
}

// streaming pack + atomic-free scatter: slot = off[dst] + rank[e]
__global__ void edge_pack(const int* __restrict__ ei, const float* __restrict__ pseudo,
                          const float* __restrict__ x,
                          const int* __restrict__ rank, const int* __restrict__ off,
                          float4* __restrict__ rec4, int* __restrict__ recb, int E){
    int e = blockIdx.x*blockDim.x + threadIdx.x;
    if (e >= E) return;
    float p0 = pseudo[3*e], p1 = pseudo[3*e+1], p2 = pseudo[3*e+2];
    int s = ei[e], d = ei[E + e];
    float v0 = p0*4.f, v1 = p1*4.f, v2 = p2*4.f;
    float f0 = fminf(fmaxf(floorf(v0), 0.f), 3.f);
    float f1 = fminf(fmaxf(floorf(v1), 0.f), 3.f);
    float f2 = fminf(fmaxf(floorf(v2), 0.f), 3.f);
    int slot = off[d] + rank[e];
    rec4[slot] = make_float4(v0 - f0, v1 - f1, v2 - f2, x[s]);
    recb[slot] = ((int)f0*5 + (int)f1)*5 + (int)f2;
}

__device__ __forceinline__ int voxel_id(const float* __restrict__ pos, int n, int G,
                                        float start, float size){
    int g[3];
    #pragma unroll
    for (int k = 0; k < 3; k++){
        float gg = floorf((pos[(size_t)n*3 + k] - start) / size);
        gg = fminf(fmaxf(gg, 0.f), (float)(G - 1));
        g[k] = (int)gg;
    }
    return (g[0]*G + g[1])*G + g[2];
}

__device__ __forceinline__ void pool_geom(const unsigned* mm, int G, int mode,
                                          float& start, float& size){
    float mn = u2f_(mm[0]), mx = u2f_(mm[1]);
    if (mode == 0){ start = mn; size = (mx + 0.001f - mn) / (float)G; }
    else          { start = mn - 0.5f; size = mx - mn + 1.0f; }
}

// ===== fused spline gather + node finalize: 8 lanes per node (tid = n*8+k) =====
__global__ __launch_bounds__(256)
void spline_node_kernel(const float* __restrict__ x, const float4* __restrict__ rec4,
                        const int* __restrict__ recb, const int* __restrict__ off,
                        const float* __restrict__ W,
                        const float* __restrict__ root, const float* __restrict__ bias,
                        const float* __restrict__ lin_w, const float* __restrict__ lin_b,
                        float* __restrict__ pose, float* __restrict__ act, int N){
    __shared__ float Ws[125*17];
    for (int i = threadIdx.x; i < 125*16; i += blockDim.x)
        Ws[(i >> 4)*17 + (i & 15)] = W[i];
    __syncthreads();
    int t = blockIdx.x*blockDim.x + threadIdx.x;
    int n = t >> 3;
    int k = t & 7;
    if (n >= N) return;     // group-uniform guard (all 8 lanes share n)

    int o0 = off[n], o1 = off[n+1];

    float agg[16];
    #pragma unroll
    for (int o = 0; o < 16; o++) agg[o] = 0.f;

    for (int s = o0 + k; s < o1; s += 8){
        float4 rv = rec4[s];
        int base = recb[s];
        float fr0 = rv.x, fr1 = rv.y, fr2 = rv.z, xv = rv.w;
        #pragma unroll
        for (int b = 0; b < 8; b++){
            int b0 = (b >> 2) & 1, b1 = (b >> 1) & 1, b2 = b & 1;
            float w = (b0 ? fr0 : 1.f - fr0) * (b1 ? fr1 : 1.f - fr1) * (b2 ? fr2 : 1.f - fr2);
            w *= xv;
            const float* Wr = &Ws[(base + b0*25 + b1*5 + b2)*17];
            #pragma unroll
            for (int o = 0; o < 16; o++) agg[o] += w * Wr[o];
        }
    }

    #pragma unroll
    for (int o = 0; o < 16; o++){
        agg[o] += __shfl_xor(agg[o], 1);
        agg[o] += __shfl_xor(agg[o], 2);
        agg[o] += __shfl_xor(agg[o], 4);
    }

    if (k != 0) return;

    float deg = fmaxf((float)(o1 - o0), 1.0f);
    float xs = x[n];
    float qv0 = lin_b[0], qv1 = lin_b[1], qv2 = lin_b[2], qv3 = lin_b[3];
    #pragma unroll
    for (int o = 0; o < 16; o++){
        float h = agg[o] / deg + xs * root[o] + bias[o];
        float e = (h > 0.f) ? h : expm1f(h);
        qv0 += e * lin_w[o*4 + 0];
        qv1 += e * lin_w[o*4 + 1];
        qv2 += e * lin_w[o*4 + 2];
        qv3 += e * lin_w[o*4 + 3];
    }
    float inv = 1.0f / (sqrtf(qv0*qv0 + qv1*qv1 + qv2*qv2 + qv3*qv3) + EPS);
    pose[(size_t)n*4 + 0] = qv0*inv;
    pose[(size_t)n*4 + 1] = qv1*inv;
    pose[(size_t)n*4 + 2] = qv2*inv;
    pose[(size_t)n*4 + 3] = qv3*inv;
    act[n] = xs;
}

// ====== wave-level routing core (R6-verified math, 8-lane group) ======
__device__ __forceinline__ void quat_pred(const float* qq, float px, float py, float pz,
                                          float pw, float* pr){
    float qx=qq[0], qy=qq[1], qz=qq[2], qw=qq[3];
    float tx = qw*px + qx*pw + qy*pz - qz*py;
    float ty = qw*py - qx*pz + qy*pw + qz*px;
    float tz = qw*pz + qx*py - qy*px + qz*pw;
    float tw = qw*pw - qx*px - qy*py - qz*pz;
    float inv = 1.f/(sqrtf(tx*tx+ty*ty+tz*tz+tw*tw)+EPS);
    pr[0]=tx*inv; pr[1]=ty*inv; pr[2]=tz*inv; pr[3]=tw*inv;
}

template<int I>
__device__ __forceinline__ void caps_route8(const float (*pr)[4], const float* a, bool on,
                                            float* c, float& v0, float& v1,
                                            float& v2, float& v3){
    float b[I];
    #pragma unroll
    for (int i = 0; i < I; i++) b[i] = on ? 0.f : -INFINITY;
    v0=v1=v2=v3=0.f;
    #pragma unroll
    for (int t = 0; t < 3; t++){
        #pragma unroll
        for (int i = 0; i < I; i++){
            float mb = b[i];
            mb = fmaxf(mb, __shfl_xor(mb, 1));
            mb = fmaxf(mb, __shfl_xor(mb, 2));
            mb = fmaxf(mb, __shfl_xor(mb, 4));
            float e = on ? expf(b[i] - mb) : 0.f;
            float s = e;
            s += __shfl_xor(s, 1);
            s += __shfl_xor(s, 2);
            s += __shfl_xor(s, 4);
            c[i] = a[i] * e / s;
        }
        float s0=0.f, s1=0.f, s2=0.f, s3=0.f;
        #pragma unroll
        for (int i = 0; i < I; i++){
            s0 += c[i]*pr[i][0]; s1 += c[i]*pr[i][1];
            s2 += c[i]*pr[i][2]; s3 += c[i]*pr[i][3];
        }
        float inv = 1.f/(sqrtf(s0*s0+s1*s1+s2*s2+s3*s3)+EPS);
        v0=s0*inv; v1=s1*inv; v2=s2*inv; v3=s3*inv;
        if (t < 2){
            #pragma unroll
            for (int i = 0; i < I; i++)
                b[i] += pr[i][0]*v0 + pr[i][1]*v1 + pr[i][2]*v2 + pr[i][3]*v3;
        }
    }
}

// ====== caps<1,6> + caps<6,6> + pool1 elist build, fused per node ======
__global__ __launch_bounds__(256)
void caps01_kernel(const float* __restrict__ pose0, const float* __restrict__ act0,
                   const float* __restrict__ q0, const float* __restrict__ q1,
                   float* __restrict__ poseOut, float* __restrict__ actOut,
                   const float* __restrict__ pos, int* __restrict__ vhead,
                   int* __restrict__ vnxt, int N, int G,
                   const unsigned* __restrict__ mm){
    __shared__ float qn0[6*4], qn1[36*4];
    for (int t = threadIdx.x; t < 6; t += blockDim.x){
        float qa=q0[t*4],qb=q0[t*4+1],qc=q0[t*4+2],qd=q0[t*4+3];
        float inv=1.f/(sqrtf(qa*qa+qb*qb+qc*qc+qd*qd)+EPS);
        qn0[t*4]=qa*inv; qn0[t*4+1]=qb*inv; qn0[t*4+2]=qc*inv; qn0[t*4+3]=qd*inv;
    }
    for (int t = threadIdx.x; t < 36; t += blockDim.x){
        float qa=q1[t*4],qb=q1[t*4+1],qc=q1[t*4+2],qd=q1[t*4+3];
        float inv=1.f/(sqrtf(qa*qa+qb*qb+qc*qc+qd*qd)+EPS);
        qn1[t*4]=qa*inv; qn1[t*4+1]=qb*inv; qn1[t*4+2]=qc*inv; qn1[t*4+3]=qd*inv;
    }
    __syncthreads();
    int tid = blockIdx.x*blockDim.x + threadIdx.x;
    int n = tid >> 3, j = tid & 7;
    if (n >= N) return;          // group-uniform
    bool on = (j < 6);

    // layer 0 (I=1, J=6)
    float4 p0 = *reinterpret_cast<const float4*>(&pose0[(size_t)n*4]);
    float aa0[1] = { act0[n] };
    float pr0[1][4] = {{0.f,0.f,0.f,0.f}};
    if (on) quat_pred(&qn0[j*4], p0.x, p0.y, p0.z, p0.w, pr0[0]);
    float c0[1], v0x, v0y, v0z, v0w;
    caps_route8<1>(pr0, aa0, on, c0, v0x, v0y, v0z, v0w);
    float al0 = sigmoidf_(c0[0]*(pr0[0][0]*v0x + pr0[0][1]*v0y
                                + pr0[0][2]*v0z + pr0[0][3]*v0w));

    // gather layer-0 outputs from lanes 0..5
    float pi[6][4], ai[6];
    #pragma unroll
    for (int i = 0; i < 6; i++){
        pi[i][0] = __shfl(v0x, i, 8);
        pi[i][1] = __shfl(v0y, i, 8);
        pi[i][2] = __shfl(v0z, i, 8);
        pi[i][3] = __shfl(v0w, i, 8);
        ai[i]    = __shfl(al0, i, 8);
    }

    // layer 1 (I=6, J=6)
    float pr[6][4];
    #pragma unroll
    for (int i = 0; i < 6; i++){
        pr[i][0]=pr[i][1]=pr[i][2]=pr[i][3]=0.f;
        if (on) quat_pred(&qn1[(i*6+j)*4], pi[i][0], pi[i][1], pi[i][2], pi[i][3], pr[i]);
    }
    float c1[6], v1x, v1y, v1z, v1w;
    caps_route8<6>(pr, ai, on, c1, v1x, v1y, v1z, v1w);
    if (on){
        float acc = 0.f;
        #pragma unroll
        for (int i = 0; i < 6; i++)
            acc += c1[i]*(pr[i][0]*v1x + pr[i][1]*v1y + pr[i][2]*v1z + pr[i][3]*v1w);
        actOut[(size_t)n*6 + j] = sigmoidf_(acc);
        *reinterpret_cast<float4*>(&poseOut[((size_t)n*6 + j)*4]) =
            make_float4(v1x, v1y, v1z, v1w);
    }
    if (j == 0){   // pool1 linked-list build (was elist_node)
        float start, size; pool_geom(mm, G, 0, start, size);
        int vid = voxel_id(pos, n, G, start, size);
        vnxt[n] = atomicExch(&vhead[vid], n);
    }
}

// ====== pool1 gather + caps<6,8>, fused per voxel (8 lanes/voxel) ======
__global__ __launch_bounds__(256)
void pool1caps_kernel(const float* __restrict__ poseIn, const float* __restrict__ actIn,
                      const float* __restrict__ pos,
                      const int* __restrict__ head, const int* __restrict__ nxt,
                      const float* __restrict__ q3,
                      float* __restrict__ poseOut, float* __restrict__ actOut,
                      float* __restrict__ posOut, int V){
    __shared__ float qn[48*4];
    for (int t = threadIdx.x; t < 48; t += blockDim.x){
        float qa=q3[t*4],qb=q3[t*4+1],qc=q3[t*4+2],qd=q3[t*4+3];
        float inv=1.f/(sqrtf(qa*qa+qb*qb+qc*qc+qd*qd)+EPS);
        qn[t*4]=qa*inv; qn[t*4+1]=qb*inv; qn[t*4+2]=qc*inv; qn[t*4+3]=qd*inv;
    }
    __syncthreads();
    int tid = blockIdx.x*blockDim.x + threadIdx.x;
    int v = tid >> 3, j = tid & 7;
    if (v >= V) return;          // group-uniform
    bool onj = (j < 6);

    float s0=0.f,s1=0.f,s2=0.f,s3=0.f, w=0.f, ps0=0.f,ps1=0.f,ps2=0.f;
    int cnt = 0;
    for (int n = head[v]; n >= 0; n = nxt[n]){
        if (onj){
            float aj = actIn[(size_t)n*6 + j];
            float4 pb = *reinterpret_cast<const float4*>(&poseIn[((size_t)n*6 + j)*4]);
            s0 += aj*pb.x; s1 += aj*pb.y; s2 += aj*pb.z; s3 += aj*pb.w;
            w += aj;
        } else if (j == 6){
            ps0 += pos[(size_t)n*3+0]; ps1 += pos[(size_t)n*3+1]; ps2 += pos[(size_t)n*3+2];
        }
        cnt++;
    }
    float m0=0.f,m1=0.f,m2=0.f,m3=0.f;
    if (onj){
        float inv = 1.f/(sqrtf(s0*s0+s1*s1+s2*s2+s3*s3)+EPS);
        m0=s0*inv; m1=s1*inv; m2=s2*inv; m3=s3*inv;
    }
    float ag = 0.f;
    for (int n = head[v]; n >= 0; n = nxt[n]){
        if (onj){
            float aj = actIn[(size_t)n*6 + j];
            float4 pb = *reinterpret_cast<const float4*>(&poseIn[((size_t)n*6 + j)*4]);
            ag += aj*(pb.x*m0 + pb.y*m1 + pb.z*m2 + pb.w*m3);
        }
    }
    float actm = sigmoidf_(ag/(w+EPS));   // valid j<6
    if (j == 6){
        float c = (float)cnt + EPS;
        posOut[(size_t)v*3+0] = ps0/c;
        posOut[(size_t)v*3+1] = ps1/c;
        posOut[(size_t)v*3+2] = ps2/c;
    }

    // caps 6 -> 8 (all 8 lanes active)
    float pi[6][4], ai[6];
    #pragma unroll
    for (int i = 0; i < 6; i++){
        pi[i][0] = __shfl(m0, i, 8);
        pi[i][1] = __shfl(m1, i, 8);
        pi[i][2] = __shfl(m2, i, 8);
        pi[i][3] = __shfl(m3, i, 8);
        ai[i]    = __shfl(actm, i, 8);
    }
    float pr[6][4];
    #pragma unroll
    for (int i = 0; i < 6; i++)
        quat_pred(&qn[(i*8+j)*4], pi[i][0], pi[i][1], pi[i][2], pi[i][3], pr[i]);
    float c1[6], vx, vy, vz, vw;
    caps_route8<6>(pr, ai, true, c1, vx, vy, vz, vw);
    float acc = 0.f;
    #pragma unroll
    for (int i = 0; i < 6; i++)
        acc += c1[i]*(pr[i][0]*vx + pr[i][1]*vy + pr[i][2]*vz + pr[i][3]*vw);
    actOut[(size_t)v*8 + j] = sigmoidf_(acc);
    *reinterpret_cast<float4*>(&poseOut[((size_t)v*8 + j)*4]) = make_float4(vx, vy, vz, vw);
}

// ---------- pools 2-3: node-parallel LDS-privatized (proven R3 path) ----------
template<int V, int J, int CH, int NCHUNK>
__global__ void pool_priv1(const float4* __restrict__ poseIn, const float* __restrict__ actIn,
                           const float* __restrict__ posIn,
                           float* __restrict__ s, float* __restrict__ wsum,
                           float* __restrict__ cnt, float* __restrict__ psum,
                           int N, int G, int mode, const unsigned* __restrict__ mm){
    __shared__ float s_[V*CH*4];
    __shared__ float wsum_[V*CH];
    __shared__ float cnt_[V];
    __shared__ float psum_[V*3];
    const int chunk = blockIdx.x % NCHUNK;
    const int slice = blockIdx.x / NCHUNK;
    const int nslices = gridDim.x / NCHUNK;
    const int c0 = chunk * CH;

    for (int t = threadIdx.x; t < V*CH*4; t += blockDim.x) s_[t] = 0.f;
    for (int t = threadIdx.x; t < V*CH; t += blockDim.x) wsum_[t] = 0.f;
    if (chunk == 0){
        for (int t = threadIdx.x; t < V; t += blockDim.x) cnt_[t] = 0.f;
        for (int t = threadIdx.x; t < V*3; t += blockDim.x) psum_[t] = 0.f;
    }
    __syncthreads();

    float start, size; pool_geom(mm, G, mode, start, size);
    int per = (N + nslices - 1) / nslices;
    int n0 = slice * per, n1 = min(N, n0 + per);

    for (int n = n0 + (int)threadIdx.x; n < n1; n += blockDim.x){
        int vid = voxel_id(posIn, n, G, start, size);
        #pragma unroll
        for (int jj = 0; jj < CH; jj++){
            int j = c0 + jj;
            float aj = actIn[(size_t)n*J + j];
            float4 p = poseIn[(size_t)n*J + j];
            int b = (vid*CH + jj)*4;
            atomicAdd(&s_[b+0], aj*p.x);
            atomicAdd(&s_[b+1], aj*p.y);
            atomicAdd(&s_[b+2], aj*p.z);
            atomicAdd(&s_[b+3], aj*p.w);
            atomicAdd(&wsum_[vid*CH + jj], aj);
        }
        if (chunk == 0){
            atomicAdd(&cnt_[vid], 1.0f);
            atomicAdd(&psum_[vid*3+0], posIn[(size_t)n*3+0]);
            atomicAdd(&psum_[vid*3+1], posIn[(size_t)n*3+1]);
            atomicAdd(&psum_[vid*3+2], posIn[(size_t)n*3+2]);
        }
    }
    __syncthreads();

    for (int t = threadIdx.x; t < V*CH*4; t += blockDim.x){
        float val = s_[t];
        if (val != 0.f){
            int v = t / (CH*4), r = t % (CH*4);
            atomicAdd(&s[((size_t)v*J + c0)*4 + r], val);
        }
    }
    for (int t = threadIdx.x; t < V*CH; t += blockDim.x){
        float val = wsum_[t];
        if (val != 0.f){
            int v = t / CH, jj = t % CH;
            atomicAdd(&wsum[(size_t)v*J + c0 + jj], val);
        }
    }
    if (chunk == 0){
        for (int t = threadIdx.x; t < V; t += blockDim.x)
            if (cnt_[t] != 0.f) atomicAdd(&cnt[t], cnt_[t]);
        for (int t = threadIdx.x; t < V*3; t += blockDim.x)
            if (psum_[t] != 0.f) atomicAdd(&psum[t], psum_[t]);
    }
}

template<int V, int J>
__global__ void pool_priv2(const float4* __restrict__ poseIn, const float* __restrict__ actIn,
                           const float* __restrict__ posIn, const float4* __restrict__ m,
                           float* __restrict__ agacc,
                           int N, int G, int mode, const unsigned* __restrict__ mm){
    __shared__ float ag_[V*J];
    for (int t = threadIdx.x; t < V*J; t += blockDim.x) ag_[t] = 0.f;
    __syncthreads();
    float start, size; pool_geom(mm, G, mode, start, size);
    int nslices = gridDim.x;
    int per = (N + nslices - 1) / nslices;
    int n0 = blockIdx.x * per, n1 = min(N, n0 + per);
    for (int n = n0 + (int)threadIdx.x; n < n1; n += blockDim.x){
        int vid = voxel_id(posIn, n, G, start, size);
        #pragma unroll
        for (int j = 0; j < J; j++){
            float4 p  = poseIn[(size_t)n*J + j];
            float4 mv = m[(size_t)vid*J + j];
            float agree = p.x*mv.x + p.y*mv.y + p.z*mv.z + p.w*mv.w;
            atomicAdd(&ag_[vid*J + j], actIn[(size_t)n*J + j]*agree);
        }
    }
    __syncthreads();
    for (int t = threadIdx.x; t < V*J; t += blockDim.x)
        if (ag_[t] != 0.f) atomicAdd(&agacc[t], ag_[t]);
}

// pool_m + pos finalize in one kernel
__global__ void pool_m2(const float* __restrict__ s, float* __restrict__ m,
                        const float* __restrict__ cnt, const float* __restrict__ psum,
                        float* __restrict__ posOut, int V, int J){
    int t = blockIdx.x*blockDim.x + threadIdx.x;
    if (t < V*J){
        float a = s[(size_t)t*4], b = s[(size_t)t*4+1];
        float c = s[(size_t)t*4+2], d = s[(size_t)t*4+3];
        float inv = 1.0f / (sqrtf(a*a + b*b + c*c + d*d) + EPS);
        m[(size_t)t*4]   = a*inv;
        m[(size_t)t*4+1] = b*inv;
        m[(size_t)t*4+2] = c*inv;
        m[(size_t)t*4+3] = d*inv;
    }
    if (t < V){
        float c = cnt[t] + EPS;
        posOut[(size_t)t*3+0] = psum[(size_t)t*3+0] / c;
        posOut[(size_t)t*3+1] = psum[(size_t)t*3+1] / c;
        posOut[(size_t)t*3+2] = psum[(size_t)t*3+2] / c;
    }
}

// ====== cooperative caps with act-finalize fused in prologue ======
template<int I, int J, int NPB>
__global__ __launch_bounds__(NPB*I*J)
void caps_coop_fin(const float* __restrict__ poseIn, const float* __restrict__ agacc,
                   const float* __restrict__ wsum, const float* __restrict__ q,
                   float* __restrict__ poseOut, float* __restrict__ actOut, int N){
    const int IJ = I*J;
    const int tid = threadIdx.x;
    const int nl  = tid / IJ;
    const int li  = tid - nl*IJ;
    const int i   = li / J;
    const int j   = li - i*J;
    const int node = blockIdx.x*NPB + nl;
    const bool on = (node < N);

    __shared__ float redA[NPB][I*J];
    __shared__ float redB[NPB][I*J];
    __shared__ float cp[NPB][I*J*4];
    __shared__ float vsh[NPB][J*4];

    float prx=0.f, pry=0.f, prz=0.f, prw=0.f, ai=0.f;
    if (on){
        float qx = q[li*4+0], qy = q[li*4+1], qz = q[li*4+2], qw = q[li*4+3];
        float qinv = 1.0f/(sqrtf(qx*qx+qy*qy+qz*qz+qw*qw)+EPS);
        qx*=qinv; qy*=qinv; qz*=qinv; qw*=qinv;
        const float* pp = &poseIn[((size_t)node*I + i)*4];
        float rx=pp[0], ry=pp[1], rz=pp[2], rw=pp[3];
        ai = sigmoidf_(agacc[(size_t)node*I + i] / (wsum[(size_t)node*I + i] + EPS));
        float tx = qw*rx + qx*rw + qy*rz - qz*ry;
        float ty = qw*ry - qx*rz + qy*rw + qz*rx;
        float tz = qw*rz + qx*ry - qy*rx + qz*rw;
        float tw = qw*rw - qx*rx - qy*ry - qz*rz;
        float pinv = 1.0f/(sqrtf(tx*tx+ty*ty+tz*tz+tw*tw)+EPS);
        prx=tx*pinv; pry=ty*pinv; prz=tz*pinv; prw=tw*pinv;
    }

    float b = 0.f, c = 0.f;
    for (int t = 0; t < 3; t++){
        redA[nl][li] = b;
        __syncthreads();
        float mb = -INFINITY;
        #pragma unroll
        for (int jj = 0; jj < J; jj++) mb = fmaxf(mb, redA[nl][i*J+jj]);
        float e = expf(b - mb);
        redB[nl][li] = e;
        __syncthreads();
        float s = 0.f;
        #pragma unroll
        for (int jj = 0; jj < J; jj++) s += redB[nl][i*J+jj];
        c = ai * e / s;
        cp[nl][li*4+0] = c*prx; cp[nl][li*4+1] = c*pry;
        cp[nl][li*4+2] = c*prz; cp[nl][li*4+3] = c*prw;
        __syncthreads();
        for (int idx = li; idx < J*4; idx += IJ){
            int jj = idx >> 2, comp = idx & 3;
            float acc = 0.f;
            #pragma unroll
            for (int ii = 0; ii < I; ii++) acc += cp[nl][(ii*J+jj)*4+comp];
            vsh[nl][idx] = acc;
        }
        __syncthreads();
        if (li < J){
            float a0=vsh[nl][li*4], a1=vsh[nl][li*4+1], a2=vsh[nl][li*4+2], a3=vsh[nl][li*4+3];
            float inv = 1.0f/(sqrtf(a0*a0+a1*a1+a2*a2+a3*a3)+EPS);
            vsh[nl][li*4]=a0*inv; vsh[nl][li*4+1]=a1*inv;
            vsh[nl][li*4+2]=a2*inv; vsh[nl][li*4+3]=a3*inv;
        }
        __syncthreads();
        if (t < 2){
            b += prx*vsh[nl][j*4] + pry*vsh[nl][j*4+1] + prz*vsh[nl][j*4+2] + prw*vsh[nl][j*4+3];
            __syncthreads();
        } else {
            redA[nl][li] = c*(prx*vsh[nl][j*4] + pry*vsh[nl][j*4+1]
                            + prz*vsh[nl][j*4+2] + prw*vsh[nl][j*4+3]);
            __syncthreads();
            if (li < J && on){
                float acc = 0.f;
                #pragma unroll
                for (int ii = 0; ii < I; ii++) acc += redA[nl][ii*J+li];
                actOut[(size_t)node*J + li] = sigmoidf_(acc);
                poseOut[((size_t)node*J+li)*4+0] = vsh[nl][li*4+0];
                poseOut[((size_t)node*J+li)*4+1] = vsh[nl][li*4+1];
                poseOut[((size_t)node*J+li)*4+2] = vsh[nl][li*4+2];
                poseOut[((size_t)node*J+li)*4+3] = vsh[nl][li*4+3];
            }
        }
    }
}

// ====== pool4 (8 nodes -> 1 voxel) + final caps<14,10>, one block ======
__global__ __launch_bounds__(192)
void pool4final_kernel(const float* __restrict__ poseIn, const float* __restrict__ actIn,
                       const float* __restrict__ q7, float* __restrict__ out){
    const int NIN = 8, JP = 14, I = 14, J = 10;
    __shared__ float mp[JP*4], ma[JP];
    __shared__ float redA[I*J], redB[I*J], cp[I*J*4], vsh[J*4];
    int t = threadIdx.x;
    if (t < JP){            // pool4: thread-per-capsule, no atomics (R5-verified math)
        float s0=0.f,s1=0.f,s2=0.f,s3=0.f,w=0.f;
        #pragma unroll
        for (int n = 0; n < NIN; n++){
            float a = actIn[n*JP + t];
            const float* pb = &poseIn[(n*JP + t)*4];
            s0 += a*pb[0]; s1 += a*pb[1]; s2 += a*pb[2]; s3 += a*pb[3];
            w += a;
        }
        float inv = 1.f/(sqrtf(s0*s0+s1*s1+s2*s2+s3*s3)+EPS);
        s0*=inv; s1*=inv; s2*=inv; s3*=inv;
        float ag = 0.f;
        #pragma unroll
        for (int n = 0; n < NIN; n++){
            float a = actIn[n*JP + t];
            const float* pb = &poseIn[(n*JP + t)*4];
            ag += a*(pb[0]*s0 + pb[1]*s1 + pb[2]*s2 + pb[3]*s3);
        }
        ma[t] = sigmoidf_(ag / (w + EPS));
        mp[t*4+0]=s0; mp[t*4+1]=s1; mp[t*4+2]=s2; mp[t*4+3]=s3;
    }
    __syncthreads();

    bool act_thr = (t < I*J);
    int li = act_thr ? t : 0;
    int i = li / J, j = li % J;
    float prx=0.f, pry=0.f, prz=0.f, prw=0.f, ai=0.f;
    if (act_thr){
        float qx=q7[li*4],qy=q7[li*4+1],qz=q7[li*4+2],qw=q7[li*4+3];
        float qinv = 1.f/(sqrtf(qx*qx+qy*qy+qz*qz+qw*qw)+EPS);
        qx*=qinv; qy*=qinv; qz*=qinv; qw*=qinv;
        float rx=mp[i*4], ry=mp[i*4+1], rz=mp[i*4+2], rw=mp[i*4+3];
        ai = ma[i];
        float tx = qw*rx + qx*rw + qy*rz - qz*ry;
        float ty = qw*ry - qx*rz + qy*rw + qz*rx;
        float tz = qw*rz + qx*ry - qy*rx + qz*rw;
        float tw = qw*rw - qx*rx - qy*ry - qz*rz;
        float pinv = 1.f/(sqrtf(tx*tx+ty*ty+tz*tz+tw*tw)+EPS);
        prx=tx*pinv; pry=ty*pinv; prz=tz*pinv; prw=tw*pinv;
    }
    float b = 0.f, c = 0.f;
    for (int it = 0; it < 3; it++){
        if (act_thr) redA[li] = b;
        __syncthreads();
        float mb = -INFINITY;
        #pragma unroll
        for (int jj = 0; jj < J; jj++) mb = fmaxf(mb, redA[i*J+jj]);
        float e = expf(b - mb);
        if (act_thr) redB[li] = e;
        __syncthreads();
        float s = 0.f;
        #pragma unroll
        for (int jj = 0; jj < J; jj++) s += redB[i*J+jj];
        c = ai * e / s;
        if (act_thr){
            cp[li*4+0]=c*prx; cp[li*4+1]=c*pry; cp[li*4+2]=c*prz; cp[li*4+3]=c*prw;
        }
        __syncthreads();
        if (act_thr){
            for (int idx = li; idx < J*4; idx += I*J){
                int jj = idx >> 2, comp = idx & 3;
                float acc = 0.f;
                #pragma unroll
                for (int ii = 0; ii < I; ii++) acc += cp[(ii*J+jj)*4+comp];
                vsh[idx] = acc;
            }
        }
        __syncthreads();
        if (act_thr && li < J){
            float a0=vsh[li*4], a1=vsh[li*4+1], a2=vsh[li*4+2], a3=vsh[li*4+3];
            float inv = 1.f/(sqrtf(a0*a0+a1*a1+a2*a2+a3*a3)+EPS);
            vsh[li*4]=a0*inv; vsh[li*4+1]=a1*inv; vsh[li*4+2]=a2*inv; vsh[li*4+3]=a3*inv;
        }
        __syncthreads();
        if (it < 2){
            b += prx*vsh[j*4] + pry*vsh[j*4+1] + prz*vsh[j*4+2] + prw*vsh[j*4+3];
            __syncthreads();
        } else {
            if (act_thr)
                redA[li] = c*(prx*vsh[j*4] + pry*vsh[j*4+1]
                            + prz*vsh[j*4+2] + prw*vsh[j*4+3]);
            __syncthreads();
            if (act_thr && li < J){
                float acc = 0.f;
                #pragma unroll
                for (int ii = 0; ii < I; ii++) acc += redA[ii*J+li];
                out[li] = sigmoidf_(acc);
            }
        }
    }
}

extern "C" void kernel_launch(void* const* d_in, const int* in_sizes, int n_in,
                              void* d_out, int out_size, void* d_ws, size_t ws_size,
                              hipStream_t stream){
    const float* x      = (const float*)d_in[0];
    const float* pos    = (const float*)d_in[1];
    const float* pseudo = (const float*)d_in[2];
    const float* Wsp    = (const float*)d_in[3];
    const float* root   = (const float*)d_in[4];
    const float* bias   = (const float*)d_in[5];
    const float* lin_w  = (const float*)d_in[6];
    const float* lin_b  = (const float*)d_in[7];
    const float* q0     = (const float*)d_in[8];
    const float* q1     = (const float*)d_in[9];
    const float* q3     = (const float*)d_in[10];
    const float* q5     = (const float*)d_in[11];
    const float* q6     = (const float*)d_in[12];
    const float* q7     = (const float*)d_in[13];
    const int*   ei     = (const int*)d_in[14];
    const int N = in_sizes[0];
    const int E = in_sizes[2] / 3;
    const int V1 = 32768;
    const int NB = (N + 255)/256;

    char* ws = (char*)d_ws;
    size_t off = 0;
    auto alloc = [&](size_t bytes)->void*{
        void* p = ws + off;
        off += (bytes + 255) & ~(size_t)255;
        return p;
    };
    unsigned* mm   = (unsigned*)alloc(8);
    int* deg       = (int*)alloc((size_t)N*sizeof(int));
    int* erank     = (int*)alloc((size_t)E*sizeof(int));
    int* eoff      = (int*)alloc((size_t)(N+1)*sizeof(int));
    int* bsum      = (int*)alloc((size_t)(NB+1)*sizeof(int));
    float4* rec4   = (float4*)alloc((size_t)E*sizeof(float4));
    int* recb      = (int*)alloc((size_t)E*sizeof(int));
    int* vhead     = (int*)alloc((size_t)V1*sizeof(int));
    int* vnxt      = (int*)alloc((size_t)N*sizeof(int));
    float* P0  = (float*)alloc((size_t)1250000*sizeof(float));
    float* P1  = (float*)alloc((size_t)1250000*sizeof(float));
    float* A0  = (float*)alloc((size_t)310000*sizeof(float));
    float* A1  = (float*)alloc((size_t)310000*sizeof(float));
    float* PB0 = (float*)alloc((size_t)100000*sizeof(float));
    float* PB1 = (float*)alloc((size_t)100000*sizeof(float));
    size_t z0 = off;                                // zeroed pool-scratch region start
    float* vs2 = (float*)alloc((size_t)512*8*4*sizeof(float));
    float* vw2 = (float*)alloc((size_t)512*8*sizeof(float));
    float* va2 = (float*)alloc((size_t)512*8*sizeof(float));
    float* vc2 = (float*)alloc((size_t)512*sizeof(float));
    float* vp2 = (float*)alloc((size_t)512*3*sizeof(float));
    float* vs3 = (float*)alloc((size_t)8*12*4*sizeof(float));
    float* vw3 = (float*)alloc((size_t)8*12*sizeof(float));
    float* va3 = (float*)alloc((size_t)8*12*sizeof(float));
    float* vc3 = (float*)alloc((size_t)8*sizeof(float));
    float* vp3 = (float*)alloc((size_t)8*3*sizeof(float));
    size_t z1 = off;
    float* pzero = (float*)(ws + z0);
    const int PZ = (int)((z1 - z0)/sizeof(float));  // zero whole region incl. padding

    // 18 dispatches total (was ~30): launch-gap is the current bottleneck.
    init_kernel<<<256, 256, 0, stream>>>(mm, deg, N, vhead, V1, pzero, PZ);
    prep_kernel<<<512, 256, 0, stream>>>(pos, N*3, mm, ei, deg, erank, E);
    scan_bsum<<<NB, 256, 0, stream>>>(deg, bsum, N);
    scan_top<<<1, 1024, 0, stream>>>(bsum, NB);
    scan_final<<<NB, 256, 0, stream>>>(deg, bsum, eoff, N, NB);
    edge_pack<<<(E + 255)/256, 256, 0, stream>>>(ei, pseudo, x, erank, eoff, rec4, recb, E);
    spline_node_kernel<<<(8*N + 255)/256, 256, 0, stream>>>(x, rec4, recb, eoff, Wsp,
                                                            root, bias, lin_w, lin_b, P0, A0, N);

    // caps<1,6> + caps<6,6> + pool1 list build, fused
    caps01_kernel<<<(8*N + 255)/256, 256, 0, stream>>>(P0, A0, q0, q1, P1, A1,
                                                       pos, vhead, vnxt, N, 32, mm);
    // pool1 gather + caps<6,8>, fused
    pool1caps_kernel<<<(8*V1 + 255)/256, 256, 0, stream>>>(P1, A1, pos, vhead, vnxt,
                                                           q3, P0, A0, PB0, V1);

    // pool2: 32768 -> 512 (G=8), J=8
    pool_priv1<512,8,4,2><<<128, 256, 0, stream>>>((const float4*)P0, A0, PB0,
                                                   vs2, vw2, vc2, vp2, 32768, 8, 0, mm);
    pool_m2<<<16, 256, 0, stream>>>(vs2, P1, vc2, vp2, PB1, 512, 8);
    pool_priv2<512,8><<<64, 256, 0, stream>>>((const float4*)P0, A0, PB0,
                                              (const float4*)P1, va2, 32768, 8, 0, mm);
    caps_coop_fin<8,12,2><<<256, 2*96, 0, stream>>>(P1, va2, vw2, q5, P0, A0, 512);

    // pool3: 512 -> 8 (G=2), J=12
    pool_priv1<8,12,12,1><<<16, 256, 0, stream>>>((const float4*)P0, A0, PB1,
                                                  vs3, vw3, vc3, vp3, 512, 2, 0, mm);
    pool_m2<<<1, 256, 0, stream>>>(vs3, P1, vc3, vp3, PB0, 8, 12);
    pool_priv2<8,12><<<16, 256, 0, stream>>>((const float4*)P0, A0, PB1,
                                             (const float4*)P1, va3, 512, 2, 0, mm);
    caps_coop_fin<12,14,1><<<8, 168, 0, stream>>>(P1, va3, vw3, q6, P0, A0, 8);

    // pool4 + final caps<14,10>, fused single block -> d_out
    pool4final_kernel<<<1, 192, 0, stream>>>(P0, A0, q7, (float*)d_out);
}